// Round 7
// baseline (785.353 us; speedup 1.0000x reference)
//
#include <hip/hip_runtime.h>

// EmbedLoopyBP on gfx950 — round 15.
// Re-anchor: R10's exact hot path + CSR build (best measured, 673.7us).
// Only change: dispatch-count reduction with zero hot-kernel deltas.
//  - k_pi0 = k_inl + k_prep + k_hist (block-range split, independent work)
//  - k_final absorbs k_out via last-block pattern (device-scope counter,
//    __threadfence release, agent-scope yacc loads)
// 18 -> 15 dispatches. Model: k_iter duration = HBM bytes / ~3.1-3.2 TB/s.

#define NN 50000
#define NE 800000
#define NG 128
#define D 64
#define LDE 36
#define LDW 66
#define LDO 72

typedef unsigned short u16;
typedef unsigned int u32;
typedef __bf16 bf16x8 __attribute__((ext_vector_type(8)));
typedef float f32x4 __attribute__((ext_vector_type(4)));

__device__ __forceinline__ float b2f(u16 u){ u32 x=((u32)u)<<16; float f; __builtin_memcpy(&f,&x,4); return f; }
__device__ __forceinline__ u16 f2b(float f){ u32 x; __builtin_memcpy(&x,&f,4); x += 0x7fffu + ((x>>16)&1u); return (u16)(x>>16); }
__device__ __forceinline__ u32 pack2(float a, float b){ return (u32)f2b(a) | ((u32)f2b(b)<<16); }
__device__ __forceinline__ void unpack8(uint4 v, float* o){
  o[0]=b2f((u16)(v.x&0xffffu)); o[1]=b2f((u16)(v.x>>16));
  o[2]=b2f((u16)(v.y&0xffffu)); o[3]=b2f((u16)(v.y>>16));
  o[4]=b2f((u16)(v.z&0xffffu)); o[5]=b2f((u16)(v.z>>16));
  o[6]=b2f((u16)(v.w&0xffffu)); o[7]=b2f((u16)(v.w>>16));
}

// ---------------- merged: node linear + weight fragment build + dst histogram ----------------
// blocks [0,12500):        inlb = bf16(node_feat @ Wn + bn)
// blocks [12500,12524):    wcB/weB fragment-order build
// blocks [12524,15649):    histogram of dst into csr_cur
// wcB[nt][h][j][kk]: lane j loads B frag for tile nt, K-half h at wcB+nt*1024+h*512+j*8;
//   j=q*16+mr; elem kk -> Wc[(h*32+q*8+kk)*D + nt*16+mr]
// weB[nt][j][kk]: K=32, elem kk -> We[(q*8+kk)*D + nt*16+mr]
__global__ __launch_bounds__(256) void k_pi0(const float* __restrict__ nf, const float* __restrict__ Wn,
                                             const float* __restrict__ bn, const float* __restrict__ Wc,
                                             const float* __restrict__ We, const int* __restrict__ dst,
                                             u16* __restrict__ inlb, u16* __restrict__ wcB,
                                             u16* __restrict__ weB, int* __restrict__ cnt){
  const int bid = blockIdx.x;
  if (bid >= 12524){           // histogram
    int e = (bid - 12524)*256 + threadIdx.x;
    atomicAdd(&cnt[dst[e]], 1);
    return;
  }
  if (bid >= 12500){           // weight fragment build
    int i = (bid - 12500)*256 + threadIdx.x;
    if (i < 4096){
      int nt = i>>10, r = i&1023;
      int h = r>>9, r2 = r&511;
      int j = r2>>3, kk = r2&7;
      int row = nt*16 + (j&15);
      int k = h*32 + (j>>4)*8 + kk;
      wcB[i] = f2b(Wc[k*D + row]);
    }
    int t = i - 4096;
    if (t >= 0 && t < 2048){
      int nt = t>>9, r = t&511;
      int j = r>>3, kk = r&7;
      int row = nt*16 + (j&15);
      int k = (j>>4)*8 + kk;
      weB[t] = f2b(We[k*D + row]);
    }
    return;
  }
  __shared__ float w[D*D];     // node linear
  for (int i=threadIdx.x;i<D*D;i+=256) w[i]=Wn[i];
  __syncthreads();
  const int d = threadIdx.x&63;
  const int n = bid*4 + (threadIdx.x>>6);
  if (n>=NN) return;
  float v = bn[d];
  const float* row = nf + (size_t)n*D;
  #pragma unroll 8
  for (int k=0;k<D;k++) v += row[k]*w[k*D+d];
  inlb[(size_t)n*D+d] = f2b(v);
}

// ---------------- naW fp32 -> bf16 (+ optional re-zero of another buffer) ----------------
template<int ZERO>
__global__ __launch_bounds__(256) void k_cvt(const float* __restrict__ srcv, u16* __restrict__ dstb,
                                             float* __restrict__ zbuf){
  size_t i = (size_t)(blockIdx.x*256 + threadIdx.x)*4;
  float4 v = *(const float4*)(srcv + i);
  *(uint2*)(dstb + i) = make_uint2(pack2(v.x,v.y), pack2(v.z,v.w));
  if (ZERO) *(float4*)(zbuf + i) = make_float4(0.f,0.f,0.f,0.f);
}

// ---------------- imP[perm[e]] = edge_feat@We + be + inl[src[e]]  (bf16) ----------------
// barrier-free: efs/os rows wave-local; B from global weB (L1-hot)
__global__ __launch_bounds__(256) void k_im(const float* __restrict__ ef, const u16* __restrict__ weB,
                                            const float* __restrict__ be, const u16* __restrict__ inlb,
                                            const int* __restrict__ src, const int* __restrict__ perm,
                                            u16* __restrict__ imP){
  __shared__ __align__(16) u16 efs[64*LDE];
  __shared__ float os[64*68];
  const int t = threadIdx.x;
  const int ebase = blockIdx.x*64;
  { // stage edge_feat bf16 (coalesced float4 reads); wave-local rows
    int e=t>>2, k0=(t&3)*8;
    const float* p = ef + (size_t)(ebase+e)*32 + k0;
    float4 v0=*(const float4*)p, v1=*(const float4*)(p+4);
    uint4 pk = make_uint4(pack2(v0.x,v0.y),pack2(v0.z,v0.w),pack2(v1.x,v1.y),pack2(v1.z,v1.w));
    *(uint4*)&efs[e*LDE + k0] = pk;
  }
  { // MFMA 16x16x32 (K=32, one step); B fragments from global, coalesced
    int w=t>>6, lane=t&63, q=lane>>4, mr=lane&15;
    int rowb=w*16;
    bf16x8 A = *(const bf16x8*)&efs[(rowb+mr)*LDE + q*8];
    #pragma unroll
    for (int nt=0;nt<4;nt++){
      bf16x8 B = *(const bf16x8*)(weB + nt*512 + lane*8);
      f32x4 acc = {0.f,0.f,0.f,0.f};
      acc = __builtin_amdgcn_mfma_f32_16x16x32_bf16(A,B,acc,0,0,0);
      #pragma unroll
      for (int r=0;r<4;r++) os[(rowb+q*4+r)*68 + nt*16+mr] = acc[r];
    }
  }
  { // epilogue: + be + inlb[src[e]] -> bf16, full-row scatter to imP[perm[e]]
    int e=t>>2, d0=(t&3)*16;
    const size_t eg = (size_t)(ebase+e);
    const int s = src[eg], ps = perm[eg];
    const u16* ip = inlb + (size_t)s*D + d0;
    uint4 iv0 = *(const uint4*)ip, iv1 = *(const uint4*)(ip+8);
    float il[16]; unpack8(iv0,il); unpack8(iv1,il+8);
    float x[16];
    #pragma unroll
    for (int j=0;j<16;j++) x[j] = os[e*68 + d0 + j] + be[d0+j] + il[j];
    uint4 p0 = make_uint4(pack2(x[0],x[1]),pack2(x[2],x[3]),pack2(x[4],x[5]),pack2(x[6],x[7]));
    uint4 p1 = make_uint4(pack2(x[8],x[9]),pack2(x[10],x[11]),pack2(x[12],x[13]),pack2(x[14],x[15]));
    u16* op = imP + (size_t)ps*D + d0;
    *(uint4*)op = p0; *(uint4*)(op+8) = p1;
  }
}

// ---------------- iteration kernel: 64 slots/block, ZERO barriers ----------------
// MODE 0: x=relu(imP[slot]);                                revOut[prevP[slot]]=(x@Wc); naW_out += per-node
// MODE 1: x=relu(naWb[srcP] (bf16) - revIn[slot]+bc+imP[slot]); same outputs
template<int MODE>
__global__ __launch_bounds__(256) void k_iter(const u16* __restrict__ imP, const u16* __restrict__ revIn,
      const u16* __restrict__ naWb, const u16* __restrict__ wcB, const float* __restrict__ bc,
      const int* __restrict__ srcP, const int* __restrict__ prevP, const int* __restrict__ nodeP,
      u16* __restrict__ revOut, float* __restrict__ naW_out){
  __shared__ __align__(16) u16 xs[64*LDW];
  __shared__ __align__(16) u16 os[64*LDO];
  __shared__ int nid[64];
  const int t = threadIdx.x;
  const int lane = t&63, w = t>>6;
  const size_t sbase = (size_t)blockIdx.x*64;
  if (lane < 16) nid[w*16 + lane] = nodeP[sbase + w*16 + lane];   // wave-local
  { // phase 1: stream reads + bf16 naWb row gather; xs rows wave-local
    const int e = t>>2, d0 = (t&3)*16;
    const size_t slot = sbase + e;
    const u16* ip = imP + slot*D + d0;
    uint4 r0 = *(const uint4*)ip, r1 = *(const uint4*)(ip+8);
    float x[16]; unpack8(r0,x); unpack8(r1,x+8);
    if (MODE == 1){
      const int sp = srcP[slot];
      const u16* cp = revIn + slot*D + d0;
      uint4 c0=*(const uint4*)cp, c1=*(const uint4*)(cp+8);
      const u16* np_ = naWb + (size_t)sp*D + d0;
      uint4 n0=*(const uint4*)np_, n1=*(const uint4*)(np_+8);
      float cv[16], nv[16];
      unpack8(c0,cv); unpack8(c1,cv+8);
      unpack8(n0,nv); unpack8(n1,nv+8);
      #pragma unroll
      for (int j=0;j<16;j++) x[j] += nv[j] - cv[j] + bc[d0+j];
    }
    #pragma unroll
    for (int j=0;j<16;j++) x[j] = x[j]>0.f ? x[j] : 0.f;
    uint4 p0 = make_uint4(pack2(x[0],x[1]),pack2(x[2],x[3]),pack2(x[4],x[5]),pack2(x[6],x[7]));
    uint4 p1 = make_uint4(pack2(x[8],x[9]),pack2(x[10],x[11]),pack2(x[12],x[13]),pack2(x[14],x[15]));
    u16* qd = &xs[e*LDW + d0];
    *(uint4*)qd = p0; *(uint4*)(qd+8) = p1;
  }
  { // phase 2: MFMA (xs wave-local); B from global wcB; scatter store + fused agg
    const int q = lane>>4, mr = lane&15;
    const int rowb = w*16;
    bf16x8 A0 = *(const bf16x8*)&xs[(rowb+mr)*LDW + q*8];
    bf16x8 A1 = *(const bf16x8*)&xs[(rowb+mr)*LDW + 32 + q*8];
    #pragma unroll
    for (int nt=0;nt<4;nt++){
      bf16x8 B0 = *(const bf16x8*)(wcB + nt*1024 + lane*8);
      bf16x8 B1 = *(const bf16x8*)(wcB + nt*1024 + 512 + lane*8);
      f32x4 acc = {0.f,0.f,0.f,0.f};
      acc = __builtin_amdgcn_mfma_f32_16x16x32_bf16(A0,B0,acc,0,0,0);
      acc = __builtin_amdgcn_mfma_f32_16x16x32_bf16(A1,B1,acc,0,0,0);
      #pragma unroll
      for (int r=0;r<4;r++) os[(rowb+q*4+r)*LDO + nt*16 + mr] = f2b(acc[r]);
    }
    const int lr = lane>>2, cc = lane&3;
    const int tgt = prevP[sbase + rowb + lr];
    u16* gp = revOut + (size_t)tgt*D + cc*16;
    *(uint4*)gp     = *(const uint4*)&os[(rowb+lr)*LDO + cc*16];
    *(uint4*)(gp+8) = *(const uint4*)&os[(rowb+lr)*LDO + cc*16 + 8];
    // fused per-node reduction (wave-local os + nid)
    float acc = 0.f;
    int curn = nid[rowb];
    #pragma unroll 4
    for (int i=0;i<16;++i){
      int n = nid[rowb+i];                 // wave-uniform
      if (n != curn){
        atomicAdd(&naW_out[(size_t)curn*D + lane], acc);
        curn = n; acc = 0.f;
      }
      acc += b2f(os[(rowb+i)*LDO + lane]);
    }
    atomicAdd(&naW_out[(size_t)curn*D + lane], acc);
  }
}

// ---------------- final BP step (barrier-free): e2n += per-node ----------------
__global__ __launch_bounds__(256) void k_last(const u16* __restrict__ imP, const u16* __restrict__ revIn,
      const u16* __restrict__ naWb, const float* __restrict__ bc,
      const int* __restrict__ srcP, const int* __restrict__ nodeP,
      float* __restrict__ e2n){
  __shared__ __align__(16) u16 xs[64*LDW];
  __shared__ int nid[64];
  const int t = threadIdx.x;
  const int lane = t&63, w = t>>6;
  const size_t sbase = (size_t)blockIdx.x*64;
  if (lane < 16) nid[w*16+lane] = nodeP[sbase + w*16 + lane];   // wave-local
  {
    const int e = t>>2, d0 = (t&3)*16;
    const size_t slot = sbase + e;
    const u16* ip = imP + slot*D + d0;
    uint4 r0 = *(const uint4*)ip, r1 = *(const uint4*)(ip+8);
    float x[16]; unpack8(r0,x); unpack8(r1,x+8);
    const int sp = srcP[slot];
    const u16* cp = revIn + slot*D + d0;
    uint4 c0 = *(const uint4*)cp, c1 = *(const uint4*)(cp+8);
    const u16* np_ = naWb + (size_t)sp*D + d0;
    uint4 n0 = *(const uint4*)np_, n1 = *(const uint4*)(np_+8);
    float cv[16], nv[16];
    unpack8(c0,cv); unpack8(c1,cv+8);
    unpack8(n0,nv); unpack8(n1,nv+8);
    #pragma unroll
    for (int j=0;j<16;j++){ x[j] += nv[j] - cv[j] + bc[d0+j]; x[j] = x[j]>0.f ? x[j] : 0.f; }
    uint4 p0 = make_uint4(pack2(x[0],x[1]),pack2(x[2],x[3]),pack2(x[4],x[5]),pack2(x[6],x[7]));
    uint4 p1 = make_uint4(pack2(x[8],x[9]),pack2(x[10],x[11]),pack2(x[12],x[13]),pack2(x[14],x[15]));
    u16* qd = &xs[e*LDW + d0];
    *(uint4*)qd = p0; *(uint4*)(qd+8) = p1;
  }
  { // wave-local reduction, no barrier
    float acc = 0.f;
    int curn = nid[w*16];
    #pragma unroll 4
    for (int i=0;i<16;++i){
      int n = nid[w*16+i];
      if (n != curn){
        atomicAdd(&e2n[(size_t)curn*D + lane], acc);
        curn = n; acc = 0.f;
      }
      acc += b2f(xs[(w*16+i)*LDW + lane]);
    }
    atomicAdd(&e2n[(size_t)curn*D + lane], acc);
  }
}

// ---------------- CSR build (R10 form) ----------------
__global__ __launch_bounds__(1024) void k_scan1(const int* __restrict__ cnt, int* __restrict__ outv,
                                                int* __restrict__ bsums, int n){
  __shared__ int sh[1024];
  int i = blockIdx.x*1024 + threadIdx.x;
  int v = (i<n)? cnt[i] : 0;
  sh[threadIdx.x]=v;
  __syncthreads();
  for (int off=1; off<1024; off<<=1){
    int tv = (threadIdx.x>=(unsigned)off)? sh[threadIdx.x-off] : 0;
    __syncthreads();
    sh[threadIdx.x] += tv;
    __syncthreads();
  }
  if (i<n) outv[i] = sh[threadIdx.x] - v;
  if (threadIdx.x==1023) bsums[blockIdx.x] = sh[1023];
}
__global__ __launch_bounds__(1024) void k_scan3(int* __restrict__ off, int* __restrict__ cur,
                                                const int* __restrict__ bsums, int n){
  __shared__ int spref;
  if (threadIdx.x < 64){
    int v = ((int)threadIdx.x < (int)blockIdx.x) ? bsums[threadIdx.x] : 0;
    #pragma unroll
    for (int o=1;o<64;o<<=1) v += __shfl_xor(v, o, 64);
    if (threadIdx.x==0) spref = v;
  }
  __syncthreads();
  int i = blockIdx.x*1024 + threadIdx.x;
  if (i<n){ int v = off[i] + spref; off[i]=v; cur[i]=v; }
}
__global__ void k_fill(const int* __restrict__ dst, const int* __restrict__ src,
                       int* __restrict__ cur, int* __restrict__ perm,
                       int* __restrict__ srcP, int* __restrict__ nodeP){
  int e = blockIdx.x*256 + threadIdx.x;
  int d = dst[e];
  int pos = atomicAdd(&cur[d], 1);
  perm[e] = pos;
  srcP[pos] = src[e];
  nodeP[pos] = d;
}
__global__ void k_prev(const int* __restrict__ rev, const int* __restrict__ perm, int* __restrict__ prevP){
  int e = blockIdx.x*256 + threadIdx.x;
  prevP[perm[e]] = perm[rev[e]];
}

// ---------------- final: relu(e2n)@Wo+bo -> relu -> graph segsum -> (last block) relu+out ----------------
__global__ __launch_bounds__(256) void k_final(const float* __restrict__ e2n, const float* __restrict__ Wo,
                                               const float* __restrict__ bo, const int* __restrict__ gid,
                                               float* __restrict__ yacc, int* __restrict__ cnt,
                                               float* __restrict__ outp){
  __shared__ float w[D*D];
  __shared__ int ticket;
  for (int i=threadIdx.x;i<D*D;i+=256) w[i]=Wo[i];
  __syncthreads();
  const int d = threadIdx.x&63, sub = threadIdx.x>>6;
  const int n0 = blockIdx.x*32 + sub*8;
  const float bod = bo[d];
  float acc=0.f; int curg=-1;
  for (int i=0;i<8;i++){
    int n=n0+i;
    if (n>=NN) break;
    int g = gid[n];
    if (g!=curg){ if (curg>=0) atomicAdd(&yacc[curg*D+d], acc); curg=g; acc=0.f; }
    float v=bod;
    const float* er = e2n + (size_t)n*D;
    #pragma unroll 8
    for (int k=0;k<D;k++){ float h=er[k]; h = h>0.f?h:0.f; v += h*w[k*D+d]; }
    acc += (v>0.f ? v : 0.f);
  }
  if (curg>=0) atomicAdd(&yacc[curg*D+d], acc);
  // last-block epilogue: relu(yacc) -> outp
  __threadfence();                                  // release our yacc atomics
  __syncthreads();
  if (threadIdx.x==0) ticket = atomicAdd(cnt, 1);
  __syncthreads();
  if (ticket == (int)gridDim.x - 1){
    __threadfence();                                // acquire
    for (int i=threadIdx.x; i<NG*D; i+=256){
      float v = __hip_atomic_load(&yacc[i], __ATOMIC_RELAXED, __HIP_MEMORY_SCOPE_AGENT);
      outp[i] = v>0.f ? v : 0.f;
    }
  }
}

// ---------------- workspace layout ----------------
static constexpr size_t SZ_E   = (size_t)NE*D*2;          // 102.4 MB bf16 edge array
static constexpr size_t SZ_NF4 = (size_t)NN*D*4;          // 12.8 MB fp32 node array
static constexpr size_t SZ_NB  = (size_t)NN*D*2;          // 6.4 MB bf16 node array
static constexpr size_t OFF_IMP  = 0;
static constexpr size_t OFF_RVA  = SZ_E;
static constexpr size_t OFF_RVB  = 2*SZ_E;
// contiguous zero region: csr_cur | naW0 | naW1 | e2n | yacc | counter
static constexpr size_t OFF_CCUR = 3*SZ_E;
static constexpr size_t OFF_NA0  = OFF_CCUR + 200064;
static constexpr size_t OFF_NA1  = OFF_NA0 + SZ_NF4;
static constexpr size_t OFF_E2N  = OFF_NA1 + SZ_NF4;
static constexpr size_t OFF_YACC = OFF_E2N + SZ_NF4;
static constexpr size_t OFF_CNT  = OFF_YACC + (size_t)NG*D*4;
static constexpr size_t ZERO_SZ  = 200064 + 3*SZ_NF4 + (size_t)NG*D*4 + 64;
static constexpr size_t OFF_NAB  = OFF_CNT + 64;                // bf16 naW
static constexpr size_t OFF_INL  = OFF_NAB + SZ_NB;
static constexpr size_t OFF_COFF = OFF_INL + SZ_NB;
static constexpr size_t OFF_PERM = OFF_COFF + 200064;
static constexpr size_t OFF_SRCP = OFF_PERM + (size_t)NE*4;
static constexpr size_t OFF_PRVP = OFF_SRCP + (size_t)NE*4;
static constexpr size_t OFF_NODP = OFF_PRVP + (size_t)NE*4;
static constexpr size_t OFF_BS   = OFF_NODP + (size_t)NE*4;
static constexpr size_t OFF_WCT  = OFF_BS + 256;               // wcB: 8192 B
static constexpr size_t OFF_WET  = OFF_WCT + 8192;             // weB: 4096 B

extern "C" void kernel_launch(void* const* d_in, const int* in_sizes, int n_in,
                              void* d_out, int out_size, void* d_ws, size_t ws_size,
                              hipStream_t stream) {
  const float* node_feat = (const float*)d_in[0];
  const float* edge_feat = (const float*)d_in[1];
  const int*   src       = (const int*)d_in[2];
  const int*   dst       = (const int*)d_in[3];
  const int*   rev       = (const int*)d_in[4];
  const int*   gid       = (const int*)d_in[5];
  const float* Wn = (const float*)d_in[7];
  const float* bn = (const float*)d_in[8];
  const float* We = (const float*)d_in[9];
  const float* be = (const float*)d_in[10];
  const float* Wc = (const float*)d_in[11];
  const float* bc = (const float*)d_in[12];
  const float* Wo = (const float*)d_in[13];
  const float* bo = (const float*)d_in[14];

  char* ws = (char*)d_ws;
  u16*   imP     = (u16*)(ws + OFF_IMP);
  u16*   revA    = (u16*)(ws + OFF_RVA);
  u16*   revB    = (u16*)(ws + OFF_RVB);
  float* naW0    = (float*)(ws + OFF_NA0);
  float* naW1    = (float*)(ws + OFF_NA1);
  float* e2n     = (float*)(ws + OFF_E2N);
  float* yacc    = (float*)(ws + OFF_YACC);
  int*   fcnt    = (int*)(ws + OFF_CNT);
  u16*   naWb    = (u16*)(ws + OFF_NAB);
  u16*   inlb    = (u16*)(ws + OFF_INL);
  int*   csr_off = (int*)(ws + OFF_COFF);
  int*   csr_cur = (int*)(ws + OFF_CCUR);
  int*   perm    = (int*)(ws + OFF_PERM);
  int*   srcP    = (int*)(ws + OFF_SRCP);
  int*   prevP   = (int*)(ws + OFF_PRVP);
  int*   nodeP   = (int*)(ws + OFF_NODP);
  int*   bsums   = (int*)(ws + OFF_BS);
  u16*   wcB     = (u16*)(ws + OFF_WCT);
  u16*   weB     = (u16*)(ws + OFF_WET);

  // one upfront memset: csr_cur + naW0 + naW1 + e2n + yacc + counter
  hipMemsetAsync(ws + OFF_CCUR, 0, ZERO_SZ, stream);

  // merged: node linear + weight fragments + dst histogram
  k_pi0<<<15649, 256, 0, stream>>>(node_feat, Wn, bn, Wc, We, dst, inlb, wcB, weB, csr_cur);

  // CSR build (R10 form)
  k_scan1<<<49, 1024, 0, stream>>>(csr_cur, csr_off, bsums, NN);
  k_scan3<<<49, 1024, 0, stream>>>(csr_off, csr_cur, bsums, NN);
  k_fill <<<NE/256, 256, 0, stream>>>(dst, src, csr_cur, perm, srcP, nodeP);
  k_prev <<<NE/256, 256, 0, stream>>>(rev, perm, prevP);

  // front end
  k_im  <<<NE/64, 256, 0, stream>>>(edge_feat, weB, be, inlb, src, perm, imP);

  // loopy BP (bf16 naWb consumption; k_cvt converts + fuses re-zero)
  k_iter<0><<<NE/64, 256, 0, stream>>>(imP, revA, naWb, wcB, bc, srcP, prevP, nodeP, revA, naW0);
  k_cvt<0><<<3125, 256, 0, stream>>>(naW0, naWb, (float*)nullptr);
  k_iter<1><<<NE/64, 256, 0, stream>>>(imP, revA, naWb, wcB, bc, srcP, prevP, nodeP, revB, naW1);
  k_cvt<1><<<3125, 256, 0, stream>>>(naW1, naWb, naW0);     // convert + re-zero naW0
  k_iter<1><<<NE/64, 256, 0, stream>>>(imP, revB, naWb, wcB, bc, srcP, prevP, nodeP, revA, naW0);
  k_cvt<0><<<3125, 256, 0, stream>>>(naW0, naWb, (float*)nullptr);
  k_last<<<NE/64, 256, 0, stream>>>(imP, revA, naWb, bc, srcP, nodeP, e2n);

  // head (k_out absorbed via last-block pattern)
  k_final<<<(NN+31)/32, 256, 0, stream>>>(e2n, Wo, bo, gid, yacc, fcnt, (float*)d_out);
}

// Round 8
// 675.203 us; speedup vs baseline: 1.1631x; 1.1631x over previous
//
#include <hip/hip_runtime.h>

// EmbedLoopyBP on gfx950 — round 16.
// Exact restore of R10 (best measured: 673.7us). All deviations R11-R15
// regressed with understood mechanisms:
//  - fp32 naW direct read: +45MB FETCH = +14us/iter (R9)
//  - separate agg pass: +430MB logical (R11)
//  - gather-read twin exchange: +13us/dispatch latency exposure (R12)
//  - imf2 fusion + LDS tricks: net-neutral-to-negative (R12-R14)
//  - per-block agent fences (last-block pattern / coop sync): buffer_wbl2
//    L2 writeback per block, +80us on k_final (R15)
// Model: hot-kernel dur = HBM bytes / ~3.1-3.2 TB/s; ~140us inter-dispatch
// is runtime cache maintenance between dependent dispatches (not removable
// by merging without paying the same flush in-kernel).

#define NN 50000
#define NE 800000
#define NG 128
#define D 64
#define LDE 36
#define LDW 66
#define LDO 72

typedef unsigned short u16;
typedef unsigned int u32;
typedef __bf16 bf16x8 __attribute__((ext_vector_type(8)));
typedef float f32x4 __attribute__((ext_vector_type(4)));

__device__ __forceinline__ float b2f(u16 u){ u32 x=((u32)u)<<16; float f; __builtin_memcpy(&f,&x,4); return f; }
__device__ __forceinline__ u16 f2b(float f){ u32 x; __builtin_memcpy(&x,&f,4); x += 0x7fffu + ((x>>16)&1u); return (u16)(x>>16); }
__device__ __forceinline__ u32 pack2(float a, float b){ return (u32)f2b(a) | ((u32)f2b(b)<<16); }
__device__ __forceinline__ void unpack8(uint4 v, float* o){
  o[0]=b2f((u16)(v.x&0xffffu)); o[1]=b2f((u16)(v.x>>16));
  o[2]=b2f((u16)(v.y&0xffffu)); o[3]=b2f((u16)(v.y>>16));
  o[4]=b2f((u16)(v.z&0xffffu)); o[5]=b2f((u16)(v.z>>16));
  o[6]=b2f((u16)(v.w&0xffffu)); o[7]=b2f((u16)(v.w>>16));
}

// ---------------- one-time weight fragment-order convert ----------------
// wcB[nt][h][j][kk] (4x2x64x8 u16): lane j loads its B fragment for tile nt,
// K-half h as 8 contiguous bf16 at wcB+nt*1024+h*512+j*8.
//   j=q*16+mr; element kk -> Wc[(h*32+q*8+kk)*D + nt*16+mr]
// weB[nt][j][kk] (4x64x8 u16): K=32, element kk -> We[(q*8+kk)*D + nt*16+mr]
__global__ __launch_bounds__(256) void k_prep(const float* __restrict__ Wc, const float* __restrict__ We,
                                              u16* __restrict__ wcB, u16* __restrict__ weB){
  int i = blockIdx.x*256 + threadIdx.x;
  if (i < 4096){
    int nt = i>>10, r = i&1023;
    int h = r>>9, r2 = r&511;
    int j = r2>>3, kk = r2&7;
    int row = nt*16 + (j&15);
    int k = h*32 + (j>>4)*8 + kk;
    wcB[i] = f2b(Wc[k*D + row]);
  }
  int t = i - 4096;
  if (t >= 0 && t < 2048){
    int nt = t>>9, r = t&511;
    int j = r>>3, kk = r&7;
    int row = nt*16 + (j&15);
    int k = (j>>4)*8 + kk;
    weB[t] = f2b(We[k*D + row]);
  }
}

// ---------------- naW fp32 -> bf16 (+ optional re-zero of another buffer) ----------------
template<int ZERO>
__global__ __launch_bounds__(256) void k_cvt(const float* __restrict__ srcv, u16* __restrict__ dstb,
                                             float* __restrict__ zbuf){
  size_t i = (size_t)(blockIdx.x*256 + threadIdx.x)*4;
  float4 v = *(const float4*)(srcv + i);
  *(uint2*)(dstb + i) = make_uint2(pack2(v.x,v.y), pack2(v.z,v.w));
  if (ZERO) *(float4*)(zbuf + i) = make_float4(0.f,0.f,0.f,0.f);
}

// ---------------- node linear: inlb = bf16(node_feat @ Wn + bn) ----------------
__global__ __launch_bounds__(256) void k_inl(const float* __restrict__ nf, const float* __restrict__ Wn,
                                             const float* __restrict__ bn, u16* __restrict__ inlb){
  __shared__ float w[D*D];
  for (int i=threadIdx.x;i<D*D;i+=256) w[i]=Wn[i];
  __syncthreads();
  const int d = threadIdx.x&63;
  const int n = blockIdx.x*4 + (threadIdx.x>>6);
  if (n>=NN) return;
  float v = bn[d];
  const float* row = nf + (size_t)n*D;
  #pragma unroll 8
  for (int k=0;k<D;k++) v += row[k]*w[k*D+d];
  inlb[(size_t)n*D+d] = f2b(v);
}

// ---------------- imP[perm[e]] = edge_feat@We + be + inl[src[e]]  (bf16) ----------------
// barrier-free: efs/os rows wave-local; B from global weB (L1-hot)
__global__ __launch_bounds__(256) void k_im(const float* __restrict__ ef, const u16* __restrict__ weB,
                                            const float* __restrict__ be, const u16* __restrict__ inlb,
                                            const int* __restrict__ src, const int* __restrict__ perm,
                                            u16* __restrict__ imP){
  __shared__ __align__(16) u16 efs[64*LDE];
  __shared__ float os[64*68];
  const int t = threadIdx.x;
  const int ebase = blockIdx.x*64;
  { // stage edge_feat bf16 (coalesced float4 reads); wave-local rows
    int e=t>>2, k0=(t&3)*8;
    const float* p = ef + (size_t)(ebase+e)*32 + k0;
    float4 v0=*(const float4*)p, v1=*(const float4*)(p+4);
    uint4 pk = make_uint4(pack2(v0.x,v0.y),pack2(v0.z,v0.w),pack2(v1.x,v1.y),pack2(v1.z,v1.w));
    *(uint4*)&efs[e*LDE + k0] = pk;
  }
  { // MFMA 16x16x32 (K=32, one step); B fragments from global, coalesced
    int w=t>>6, lane=t&63, q=lane>>4, mr=lane&15;
    int rowb=w*16;
    bf16x8 A = *(const bf16x8*)&efs[(rowb+mr)*LDE + q*8];
    #pragma unroll
    for (int nt=0;nt<4;nt++){
      bf16x8 B = *(const bf16x8*)(weB + nt*512 + lane*8);
      f32x4 acc = {0.f,0.f,0.f,0.f};
      acc = __builtin_amdgcn_mfma_f32_16x16x32_bf16(A,B,acc,0,0,0);
      #pragma unroll
      for (int r=0;r<4;r++) os[(rowb+q*4+r)*68 + nt*16+mr] = acc[r];
    }
  }
  { // epilogue: + be + inlb[src[e]] -> bf16, full-row scatter to imP[perm[e]]
    int e=t>>2, d0=(t&3)*16;
    const size_t eg = (size_t)(ebase+e);
    const int s = src[eg], ps = perm[eg];
    const u16* ip = inlb + (size_t)s*D + d0;
    uint4 iv0 = *(const uint4*)ip, iv1 = *(const uint4*)(ip+8);
    float il[16]; unpack8(iv0,il); unpack8(iv1,il+8);
    float x[16];
    #pragma unroll
    for (int j=0;j<16;j++) x[j] = os[e*68 + d0 + j] + be[d0+j] + il[j];
    uint4 p0 = make_uint4(pack2(x[0],x[1]),pack2(x[2],x[3]),pack2(x[4],x[5]),pack2(x[6],x[7]));
    uint4 p1 = make_uint4(pack2(x[8],x[9]),pack2(x[10],x[11]),pack2(x[12],x[13]),pack2(x[14],x[15]));
    u16* op = imP + (size_t)ps*D + d0;
    *(uint4*)op = p0; *(uint4*)(op+8) = p1;
  }
}

// ---------------- iteration kernel: 64 slots/block, ZERO barriers ----------------
// MODE 0: x=relu(imP[slot]);                                revOut[prevP[slot]]=(x@Wc); naW_out += per-node
// MODE 1: x=relu(naWb[srcP] (bf16) - revIn[slot]+bc+imP[slot]); same outputs
template<int MODE>
__global__ __launch_bounds__(256) void k_iter(const u16* __restrict__ imP, const u16* __restrict__ revIn,
      const u16* __restrict__ naWb, const u16* __restrict__ wcB, const float* __restrict__ bc,
      const int* __restrict__ srcP, const int* __restrict__ prevP, const int* __restrict__ nodeP,
      u16* __restrict__ revOut, float* __restrict__ naW_out){
  __shared__ __align__(16) u16 xs[64*LDW];
  __shared__ __align__(16) u16 os[64*LDO];
  __shared__ int nid[64];
  const int t = threadIdx.x;
  const int lane = t&63, w = t>>6;
  const size_t sbase = (size_t)blockIdx.x*64;
  if (lane < 16) nid[w*16 + lane] = nodeP[sbase + w*16 + lane];   // wave-local
  { // phase 1: stream reads + bf16 naWb row gather; xs rows wave-local
    const int e = t>>2, d0 = (t&3)*16;
    const size_t slot = sbase + e;
    const u16* ip = imP + slot*D + d0;
    uint4 r0 = *(const uint4*)ip, r1 = *(const uint4*)(ip+8);
    float x[16]; unpack8(r0,x); unpack8(r1,x+8);
    if (MODE == 1){
      const int sp = srcP[slot];
      const u16* cp = revIn + slot*D + d0;
      uint4 c0=*(const uint4*)cp, c1=*(const uint4*)(cp+8);
      const u16* np_ = naWb + (size_t)sp*D + d0;
      uint4 n0=*(const uint4*)np_, n1=*(const uint4*)(np_+8);
      float cv[16], nv[16];
      unpack8(c0,cv); unpack8(c1,cv+8);
      unpack8(n0,nv); unpack8(n1,nv+8);
      #pragma unroll
      for (int j=0;j<16;j++) x[j] += nv[j] - cv[j] + bc[d0+j];
    }
    #pragma unroll
    for (int j=0;j<16;j++) x[j] = x[j]>0.f ? x[j] : 0.f;
    uint4 p0 = make_uint4(pack2(x[0],x[1]),pack2(x[2],x[3]),pack2(x[4],x[5]),pack2(x[6],x[7]));
    uint4 p1 = make_uint4(pack2(x[8],x[9]),pack2(x[10],x[11]),pack2(x[12],x[13]),pack2(x[14],x[15]));
    u16* qd = &xs[e*LDW + d0];
    *(uint4*)qd = p0; *(uint4*)(qd+8) = p1;
  }
  { // phase 2: MFMA (xs wave-local, no barrier); scatter store + fused flush
    const int q = lane>>4, mr = lane&15;
    const int rowb = w*16;
    bf16x8 A0 = *(const bf16x8*)&xs[(rowb+mr)*LDW + q*8];
    bf16x8 A1 = *(const bf16x8*)&xs[(rowb+mr)*LDW + 32 + q*8];
    #pragma unroll
    for (int nt=0;nt<4;nt++){
      bf16x8 B0 = *(const bf16x8*)(wcB + nt*1024 + lane*8);
      bf16x8 B1 = *(const bf16x8*)(wcB + nt*1024 + 512 + lane*8);
      f32x4 acc = {0.f,0.f,0.f,0.f};
      acc = __builtin_amdgcn_mfma_f32_16x16x32_bf16(A0,B0,acc,0,0,0);
      acc = __builtin_amdgcn_mfma_f32_16x16x32_bf16(A1,B1,acc,0,0,0);
      #pragma unroll
      for (int r=0;r<4;r++) os[(rowb+q*4+r)*LDO + nt*16 + mr] = f2b(acc[r]);
    }
    const int lr = lane>>2, cc = lane&3;
    const int tgt = prevP[sbase + rowb + lr];
    u16* gp = revOut + (size_t)tgt*D + cc*16;
    *(uint4*)gp     = *(const uint4*)&os[(rowb+lr)*LDO + cc*16];
    *(uint4*)(gp+8) = *(const uint4*)&os[(rowb+lr)*LDO + cc*16 + 8];
    // fused per-node reduction (wave-local os + nid)
    float acc = 0.f;
    int curn = nid[rowb];
    #pragma unroll 4
    for (int i=0;i<16;++i){
      int n = nid[rowb+i];                 // wave-uniform
      if (n != curn){
        atomicAdd(&naW_out[(size_t)curn*D + lane], acc);
        curn = n; acc = 0.f;
      }
      acc += b2f(os[(rowb+i)*LDO + lane]);
    }
    atomicAdd(&naW_out[(size_t)curn*D + lane], acc);
  }
}

// ---------------- final BP step (barrier-free): e2n += per-node ----------------
__global__ __launch_bounds__(256) void k_last(const u16* __restrict__ imP, const u16* __restrict__ revIn,
      const u16* __restrict__ naWb, const float* __restrict__ bc,
      const int* __restrict__ srcP, const int* __restrict__ nodeP,
      float* __restrict__ e2n){
  __shared__ __align__(16) u16 xs[64*LDW];
  __shared__ int nid[64];
  const int t = threadIdx.x;
  const int lane = t&63, w = t>>6;
  const size_t sbase = (size_t)blockIdx.x*64;
  if (lane < 16) nid[w*16+lane] = nodeP[sbase + w*16 + lane];   // wave-local
  {
    const int e = t>>2, d0 = (t&3)*16;
    const size_t slot = sbase + e;
    const u16* ip = imP + slot*D + d0;
    uint4 r0 = *(const uint4*)ip, r1 = *(const uint4*)(ip+8);
    float x[16]; unpack8(r0,x); unpack8(r1,x+8);
    const int sp = srcP[slot];
    const u16* cp = revIn + slot*D + d0;
    uint4 c0 = *(const uint4*)cp, c1 = *(const uint4*)(cp+8);
    const u16* np_ = naWb + (size_t)sp*D + d0;
    uint4 n0 = *(const uint4*)np_, n1 = *(const uint4*)(np_+8);
    float cv[16], nv[16];
    unpack8(c0,cv); unpack8(c1,cv+8);
    unpack8(n0,nv); unpack8(n1,nv+8);
    #pragma unroll
    for (int j=0;j<16;j++){ x[j] += nv[j] - cv[j] + bc[d0+j]; x[j] = x[j]>0.f ? x[j] : 0.f; }
    uint4 p0 = make_uint4(pack2(x[0],x[1]),pack2(x[2],x[3]),pack2(x[4],x[5]),pack2(x[6],x[7]));
    uint4 p1 = make_uint4(pack2(x[8],x[9]),pack2(x[10],x[11]),pack2(x[12],x[13]),pack2(x[14],x[15]));
    u16* qd = &xs[e*LDW + d0];
    *(uint4*)qd = p0; *(uint4*)(qd+8) = p1;
  }
  { // wave-local reduction, no barrier
    float acc = 0.f;
    int curn = nid[w*16];
    #pragma unroll 4
    for (int i=0;i<16;++i){
      int n = nid[w*16+i];
      if (n != curn){
        atomicAdd(&e2n[(size_t)curn*D + lane], acc);
        curn = n; acc = 0.f;
      }
      acc += b2f(xs[(w*16+i)*LDW + lane]);
    }
    atomicAdd(&e2n[(size_t)curn*D + lane], acc);
  }
}

// ---------------- CSR build ----------------
__global__ void k_hist(const int* __restrict__ dst, int* __restrict__ cnt){
  int e = blockIdx.x*256 + threadIdx.x;
  atomicAdd(&cnt[dst[e]], 1);
}
__global__ __launch_bounds__(1024) void k_scan1(const int* __restrict__ cnt, int* __restrict__ outv,
                                                int* __restrict__ bsums, int n){
  __shared__ int sh[1024];
  int i = blockIdx.x*1024 + threadIdx.x;
  int v = (i<n)? cnt[i] : 0;
  sh[threadIdx.x]=v;
  __syncthreads();
  for (int off=1; off<1024; off<<=1){
    int tv = (threadIdx.x>=(unsigned)off)? sh[threadIdx.x-off] : 0;
    __syncthreads();
    sh[threadIdx.x] += tv;
    __syncthreads();
  }
  if (i<n) outv[i] = sh[threadIdx.x] - v;
  if (threadIdx.x==1023) bsums[blockIdx.x] = sh[1023];
}
__global__ __launch_bounds__(1024) void k_scan3(int* __restrict__ off, int* __restrict__ cur,
                                                const int* __restrict__ bsums, int n){
  __shared__ int spref;
  if (threadIdx.x < 64){
    int v = ((int)threadIdx.x < (int)blockIdx.x) ? bsums[threadIdx.x] : 0;
    #pragma unroll
    for (int o=1;o<64;o<<=1) v += __shfl_xor(v, o, 64);
    if (threadIdx.x==0) spref = v;
  }
  __syncthreads();
  int i = blockIdx.x*1024 + threadIdx.x;
  if (i<n){ int v = off[i] + spref; off[i]=v; cur[i]=v; }
}
__global__ void k_fill(const int* __restrict__ dst, const int* __restrict__ src,
                       int* __restrict__ cur, int* __restrict__ perm,
                       int* __restrict__ srcP, int* __restrict__ nodeP){
  int e = blockIdx.x*256 + threadIdx.x;
  int d = dst[e];
  int pos = atomicAdd(&cur[d], 1);
  perm[e] = pos;
  srcP[pos] = src[e];
  nodeP[pos] = d;
}
__global__ void k_prev(const int* __restrict__ rev, const int* __restrict__ perm, int* __restrict__ prevP){
  int e = blockIdx.x*256 + threadIdx.x;
  prevP[perm[e]] = perm[rev[e]];
}

// ---------------- final: relu(e2n)@Wo+bo -> relu -> graph segsum ----------------
__global__ __launch_bounds__(256) void k_final(const float* __restrict__ e2n, const float* __restrict__ Wo,
                                               const float* __restrict__ bo, const int* __restrict__ gid,
                                               float* __restrict__ yacc){
  __shared__ float w[D*D];
  for (int i=threadIdx.x;i<D*D;i+=256) w[i]=Wo[i];
  __syncthreads();
  const int d = threadIdx.x&63, sub = threadIdx.x>>6;
  const int n0 = blockIdx.x*32 + sub*8;
  const float bod = bo[d];
  float acc=0.f; int curg=-1;
  for (int i=0;i<8;i++){
    int n=n0+i;
    if (n>=NN) break;
    int g = gid[n];
    if (g!=curg){ if (curg>=0) atomicAdd(&yacc[curg*D+d], acc); curg=g; acc=0.f; }
    float v=bod;
    const float* er = e2n + (size_t)n*D;
    #pragma unroll 8
    for (int k=0;k<D;k++){ float h=er[k]; h = h>0.f?h:0.f; v += h*w[k*D+d]; }
    acc += (v>0.f ? v : 0.f);
  }
  if (curg>=0) atomicAdd(&yacc[curg*D+d], acc);
}
__global__ void k_out(const float* __restrict__ yacc, float* __restrict__ outp){
  int i = blockIdx.x*256 + threadIdx.x;
  if (i<NG*D){ float v=yacc[i]; outp[i]= v>0.f?v:0.f; }
}

// ---------------- workspace layout ----------------
static constexpr size_t SZ_E   = (size_t)NE*D*2;          // 102.4 MB bf16 edge array
static constexpr size_t SZ_NF4 = (size_t)NN*D*4;          // 12.8 MB fp32 node array
static constexpr size_t SZ_NB  = (size_t)NN*D*2;          // 6.4 MB bf16 node array
static constexpr size_t OFF_IMP  = 0;
static constexpr size_t OFF_RVA  = SZ_E;
static constexpr size_t OFF_RVB  = 2*SZ_E;
// contiguous zero region: csr_cur | naW0 | naW1 | e2n | yacc
static constexpr size_t OFF_CCUR = 3*SZ_E;
static constexpr size_t OFF_NA0  = OFF_CCUR + 200064;
static constexpr size_t OFF_NA1  = OFF_NA0 + SZ_NF4;
static constexpr size_t OFF_E2N  = OFF_NA1 + SZ_NF4;
static constexpr size_t OFF_YACC = OFF_E2N + SZ_NF4;
static constexpr size_t ZERO_SZ  = 200064 + 3*SZ_NF4 + (size_t)NG*D*4;
static constexpr size_t OFF_NAB  = OFF_YACC + (size_t)NG*D*4;   // bf16 naW (single reused buffer)
static constexpr size_t OFF_INL  = OFF_NAB + SZ_NB;
static constexpr size_t OFF_COFF = OFF_INL + SZ_NB;
static constexpr size_t OFF_PERM = OFF_COFF + 200064;
static constexpr size_t OFF_SRCP = OFF_PERM + (size_t)NE*4;
static constexpr size_t OFF_PRVP = OFF_SRCP + (size_t)NE*4;
static constexpr size_t OFF_NODP = OFF_PRVP + (size_t)NE*4;
static constexpr size_t OFF_BS   = OFF_NODP + (size_t)NE*4;
static constexpr size_t OFF_WCT  = OFF_BS + 256;               // wcB: 4096 u16 = 8192 B
static constexpr size_t OFF_WET  = OFF_WCT + 8192;             // weB: 2048 u16 = 4096 B

extern "C" void kernel_launch(void* const* d_in, const int* in_sizes, int n_in,
                              void* d_out, int out_size, void* d_ws, size_t ws_size,
                              hipStream_t stream) {
  const float* node_feat = (const float*)d_in[0];
  const float* edge_feat = (const float*)d_in[1];
  const int*   src       = (const int*)d_in[2];
  const int*   dst       = (const int*)d_in[3];
  const int*   rev       = (const int*)d_in[4];
  const int*   gid       = (const int*)d_in[5];
  const float* Wn = (const float*)d_in[7];
  const float* bn = (const float*)d_in[8];
  const float* We = (const float*)d_in[9];
  const float* be = (const float*)d_in[10];
  const float* Wc = (const float*)d_in[11];
  const float* bc = (const float*)d_in[12];
  const float* Wo = (const float*)d_in[13];
  const float* bo = (const float*)d_in[14];

  char* ws = (char*)d_ws;
  u16*   imP     = (u16*)(ws + OFF_IMP);
  u16*   revA    = (u16*)(ws + OFF_RVA);
  u16*   revB    = (u16*)(ws + OFF_RVB);
  float* naW0    = (float*)(ws + OFF_NA0);
  float* naW1    = (float*)(ws + OFF_NA1);
  float* e2n     = (float*)(ws + OFF_E2N);
  float* yacc    = (float*)(ws + OFF_YACC);
  u16*   naWb    = (u16*)(ws + OFF_NAB);
  u16*   inlb    = (u16*)(ws + OFF_INL);
  int*   csr_off = (int*)(ws + OFF_COFF);
  int*   csr_cur = (int*)(ws + OFF_CCUR);
  int*   perm    = (int*)(ws + OFF_PERM);
  int*   srcP    = (int*)(ws + OFF_SRCP);
  int*   prevP   = (int*)(ws + OFF_PRVP);
  int*   nodeP   = (int*)(ws + OFF_NODP);
  int*   bsums   = (int*)(ws + OFF_BS);
  u16*   wcB     = (u16*)(ws + OFF_WCT);
  u16*   weB     = (u16*)(ws + OFF_WET);

  // one upfront memset: csr_cur + naW0 + naW1 + e2n + yacc
  hipMemsetAsync(ws + OFF_CCUR, 0, ZERO_SZ, stream);

  // CSR build
  k_hist <<<NE/256, 256, 0, stream>>>(dst, csr_cur);
  k_scan1<<<49, 1024, 0, stream>>>(csr_cur, csr_off, bsums, NN);
  k_scan3<<<49, 1024, 0, stream>>>(csr_off, csr_cur, bsums, NN);
  k_fill <<<NE/256, 256, 0, stream>>>(dst, src, csr_cur, perm, srcP, nodeP);
  k_prev <<<NE/256, 256, 0, stream>>>(rev, perm, prevP);

  // weights prep + front end
  k_prep<<<24, 256, 0, stream>>>(Wc, We, wcB, weB);
  k_inl <<<NN/4, 256, 0, stream>>>(node_feat, Wn, bn, inlb);
  k_im  <<<NE/64, 256, 0, stream>>>(edge_feat, weB, be, inlb, src, perm, imP);

  // loopy BP (bf16 naWb consumption; k_cvt converts + fuses re-zero)
  k_iter<0><<<NE/64, 256, 0, stream>>>(imP, revA, naWb, wcB, bc, srcP, prevP, nodeP, revA, naW0);
  k_cvt<0><<<3125, 256, 0, stream>>>(naW0, naWb, (float*)nullptr);
  k_iter<1><<<NE/64, 256, 0, stream>>>(imP, revA, naWb, wcB, bc, srcP, prevP, nodeP, revB, naW1);
  k_cvt<1><<<3125, 256, 0, stream>>>(naW1, naWb, naW0);     // convert + re-zero naW0
  k_iter<1><<<NE/64, 256, 0, stream>>>(imP, revB, naWb, wcB, bc, srcP, prevP, nodeP, revA, naW0);
  k_cvt<0><<<3125, 256, 0, stream>>>(naW0, naWb, (float*)nullptr);
  k_last<<<NE/64, 256, 0, stream>>>(imP, revA, naWb, bc, srcP, nodeP, e2n);

  // head
  k_final<<<(NN+31)/32, 256, 0, stream>>>(e2n, Wo, bo, gid, yacc);
  k_out<<<(NG*D)/256, 256, 0, stream>>>(yacc, (float*)d_out);
}

// Round 9
// 649.406 us; speedup vs baseline: 1.2093x; 1.0397x over previous
//
#include <hip/hip_runtime.h>

// EmbedLoopyBP on gfx950 — round 17.
// R16 (= R10 anchor, 675us reproduced) with ONE isolated change:
// k_cvt stage deleted. k_iter's fused per-node reduction accumulates
// DIRECTLY into bf16 naWb via global_atomic_pk_add_bf16 (CDNA3/4 packed
// bf16 atomic; CK's bhalf2 atomic_add form). Even lanes pack (col,col+1)
// with __shfl_xor and issue one 4B packed atomic. Triple-buffered naWb
// (nb0/nb1/nb2, zeroed in the single upfront memset) -> no mid-stream
// re-zero, no fp32 naW buffers, 3 fewer dispatches, ~75MB less traffic.
// Everything else byte-identical to R16.

#define NN 50000
#define NE 800000
#define NG 128
#define D 64
#define LDE 36
#define LDW 66
#define LDO 72

typedef unsigned short u16;
typedef unsigned int u32;
typedef __bf16 bf16x8 __attribute__((ext_vector_type(8)));
typedef float f32x4 __attribute__((ext_vector_type(4)));
typedef short s16x2 __attribute__((ext_vector_type(2)));

__device__ __forceinline__ float b2f(u16 u){ u32 x=((u32)u)<<16; float f; __builtin_memcpy(&f,&x,4); return f; }
__device__ __forceinline__ u16 f2b(float f){ u32 x; __builtin_memcpy(&x,&f,4); x += 0x7fffu + ((x>>16)&1u); return (u16)(x>>16); }
__device__ __forceinline__ u32 pack2(float a, float b){ return (u32)f2b(a) | ((u32)f2b(b)<<16); }
__device__ __forceinline__ void unpack8(uint4 v, float* o){
  o[0]=b2f((u16)(v.x&0xffffu)); o[1]=b2f((u16)(v.x>>16));
  o[2]=b2f((u16)(v.y&0xffffu)); o[3]=b2f((u16)(v.y>>16));
  o[4]=b2f((u16)(v.z&0xffffu)); o[5]=b2f((u16)(v.z>>16));
  o[6]=b2f((u16)(v.w&0xffffu)); o[7]=b2f((u16)(v.w>>16));
}
// packed bf16 atomic add of (lo,hi) at u16-address addr (4B-aligned)
__device__ __forceinline__ void atomic_pk_bf16(u16* addr, float lo, float hi){
  s16x2 v; v.x = (short)f2b(lo); v.y = (short)f2b(hi);
  __builtin_amdgcn_global_atomic_fadd_v2bf16((s16x2*)addr, v);
}

// ---------------- one-time weight fragment-order convert ----------------
// wcB[nt][h][j][kk] (4x2x64x8 u16): lane j loads its B fragment for tile nt,
// K-half h as 8 contiguous bf16 at wcB+nt*1024+h*512+j*8.
//   j=q*16+mr; element kk -> Wc[(h*32+q*8+kk)*D + nt*16+mr]
// weB[nt][j][kk] (4x64x8 u16): K=32, element kk -> We[(q*8+kk)*D + nt*16+mr]
__global__ __launch_bounds__(256) void k_prep(const float* __restrict__ Wc, const float* __restrict__ We,
                                              u16* __restrict__ wcB, u16* __restrict__ weB){
  int i = blockIdx.x*256 + threadIdx.x;
  if (i < 4096){
    int nt = i>>10, r = i&1023;
    int h = r>>9, r2 = r&511;
    int j = r2>>3, kk = r2&7;
    int row = nt*16 + (j&15);
    int k = h*32 + (j>>4)*8 + kk;
    wcB[i] = f2b(Wc[k*D + row]);
  }
  int t = i - 4096;
  if (t >= 0 && t < 2048){
    int nt = t>>9, r = t&511;
    int j = r>>3, kk = r&7;
    int row = nt*16 + (j&15);
    int k = (j>>4)*8 + kk;
    weB[t] = f2b(We[k*D + row]);
  }
}

// ---------------- node linear: inlb = bf16(node_feat @ Wn + bn) ----------------
__global__ __launch_bounds__(256) void k_inl(const float* __restrict__ nf, const float* __restrict__ Wn,
                                             const float* __restrict__ bn, u16* __restrict__ inlb){
  __shared__ float w[D*D];
  for (int i=threadIdx.x;i<D*D;i+=256) w[i]=Wn[i];
  __syncthreads();
  const int d = threadIdx.x&63;
  const int n = blockIdx.x*4 + (threadIdx.x>>6);
  if (n>=NN) return;
  float v = bn[d];
  const float* row = nf + (size_t)n*D;
  #pragma unroll 8
  for (int k=0;k<D;k++) v += row[k]*w[k*D+d];
  inlb[(size_t)n*D+d] = f2b(v);
}

// ---------------- imP[perm[e]] = edge_feat@We + be + inl[src[e]]  (bf16) ----------------
// barrier-free: efs/os rows wave-local; B from global weB (L1-hot)
__global__ __launch_bounds__(256) void k_im(const float* __restrict__ ef, const u16* __restrict__ weB,
                                            const float* __restrict__ be, const u16* __restrict__ inlb,
                                            const int* __restrict__ src, const int* __restrict__ perm,
                                            u16* __restrict__ imP){
  __shared__ __align__(16) u16 efs[64*LDE];
  __shared__ float os[64*68];
  const int t = threadIdx.x;
  const int ebase = blockIdx.x*64;
  { // stage edge_feat bf16 (coalesced float4 reads); wave-local rows
    int e=t>>2, k0=(t&3)*8;
    const float* p = ef + (size_t)(ebase+e)*32 + k0;
    float4 v0=*(const float4*)p, v1=*(const float4*)(p+4);
    uint4 pk = make_uint4(pack2(v0.x,v0.y),pack2(v0.z,v0.w),pack2(v1.x,v1.y),pack2(v1.z,v1.w));
    *(uint4*)&efs[e*LDE + k0] = pk;
  }
  { // MFMA 16x16x32 (K=32, one step); B fragments from global, coalesced
    int w=t>>6, lane=t&63, q=lane>>4, mr=lane&15;
    int rowb=w*16;
    bf16x8 A = *(const bf16x8*)&efs[(rowb+mr)*LDE + q*8];
    #pragma unroll
    for (int nt=0;nt<4;nt++){
      bf16x8 B = *(const bf16x8*)(weB + nt*512 + lane*8);
      f32x4 acc = {0.f,0.f,0.f,0.f};
      acc = __builtin_amdgcn_mfma_f32_16x16x32_bf16(A,B,acc,0,0,0);
      #pragma unroll
      for (int r=0;r<4;r++) os[(rowb+q*4+r)*68 + nt*16+mr] = acc[r];
    }
  }
  { // epilogue: + be + inlb[src[e]] -> bf16, full-row scatter to imP[perm[e]]
    int e=t>>2, d0=(t&3)*16;
    const size_t eg = (size_t)(ebase+e);
    const int s = src[eg], ps = perm[eg];
    const u16* ip = inlb + (size_t)s*D + d0;
    uint4 iv0 = *(const uint4*)ip, iv1 = *(const uint4*)(ip+8);
    float il[16]; unpack8(iv0,il); unpack8(iv1,il+8);
    float x[16];
    #pragma unroll
    for (int j=0;j<16;j++) x[j] = os[e*68 + d0 + j] + be[d0+j] + il[j];
    uint4 p0 = make_uint4(pack2(x[0],x[1]),pack2(x[2],x[3]),pack2(x[4],x[5]),pack2(x[6],x[7]));
    uint4 p1 = make_uint4(pack2(x[8],x[9]),pack2(x[10],x[11]),pack2(x[12],x[13]),pack2(x[14],x[15]));
    u16* op = imP + (size_t)ps*D + d0;
    *(uint4*)op = p0; *(uint4*)(op+8) = p1;
  }
}

// ---------------- iteration kernel: 64 slots/block, ZERO barriers ----------------
// MODE 0: x=relu(imP[slot]);                                revOut[prevP[slot]]=(x@Wc); naWb_out += per-node (pk bf16)
// MODE 1: x=relu(naWb[srcP] (bf16) - revIn[slot]+bc+imP[slot]); same outputs
template<int MODE>
__global__ __launch_bounds__(256) void k_iter(const u16* __restrict__ imP, const u16* __restrict__ revIn,
      const u16* __restrict__ naWb, const u16* __restrict__ wcB, const float* __restrict__ bc,
      const int* __restrict__ srcP, const int* __restrict__ prevP, const int* __restrict__ nodeP,
      u16* __restrict__ revOut, u16* __restrict__ naWb_out){
  __shared__ __align__(16) u16 xs[64*LDW];
  __shared__ __align__(16) u16 os[64*LDO];
  __shared__ int nid[64];
  const int t = threadIdx.x;
  const int lane = t&63, w = t>>6;
  const size_t sbase = (size_t)blockIdx.x*64;
  if (lane < 16) nid[w*16 + lane] = nodeP[sbase + w*16 + lane];   // wave-local
  { // phase 1: stream reads + bf16 naWb row gather; xs rows wave-local
    const int e = t>>2, d0 = (t&3)*16;
    const size_t slot = sbase + e;
    const u16* ip = imP + slot*D + d0;
    uint4 r0 = *(const uint4*)ip, r1 = *(const uint4*)(ip+8);
    float x[16]; unpack8(r0,x); unpack8(r1,x+8);
    if (MODE == 1){
      const int sp = srcP[slot];
      const u16* cp = revIn + slot*D + d0;
      uint4 c0=*(const uint4*)cp, c1=*(const uint4*)(cp+8);
      const u16* np_ = naWb + (size_t)sp*D + d0;
      uint4 n0=*(const uint4*)np_, n1=*(const uint4*)(np_+8);
      float cv[16], nv[16];
      unpack8(c0,cv); unpack8(c1,cv+8);
      unpack8(n0,nv); unpack8(n1,nv+8);
      #pragma unroll
      for (int j=0;j<16;j++) x[j] += nv[j] - cv[j] + bc[d0+j];
    }
    #pragma unroll
    for (int j=0;j<16;j++) x[j] = x[j]>0.f ? x[j] : 0.f;
    uint4 p0 = make_uint4(pack2(x[0],x[1]),pack2(x[2],x[3]),pack2(x[4],x[5]),pack2(x[6],x[7]));
    uint4 p1 = make_uint4(pack2(x[8],x[9]),pack2(x[10],x[11]),pack2(x[12],x[13]),pack2(x[14],x[15]));
    u16* qd = &xs[e*LDW + d0];
    *(uint4*)qd = p0; *(uint4*)(qd+8) = p1;
  }
  { // phase 2: MFMA (xs wave-local, no barrier); scatter store + fused flush
    const int q = lane>>4, mr = lane&15;
    const int rowb = w*16;
    bf16x8 A0 = *(const bf16x8*)&xs[(rowb+mr)*LDW + q*8];
    bf16x8 A1 = *(const bf16x8*)&xs[(rowb+mr)*LDW + 32 + q*8];
    #pragma unroll
    for (int nt=0;nt<4;nt++){
      bf16x8 B0 = *(const bf16x8*)(wcB + nt*1024 + lane*8);
      bf16x8 B1 = *(const bf16x8*)(wcB + nt*1024 + 512 + lane*8);
      f32x4 acc = {0.f,0.f,0.f,0.f};
      acc = __builtin_amdgcn_mfma_f32_16x16x32_bf16(A0,B0,acc,0,0,0);
      acc = __builtin_amdgcn_mfma_f32_16x16x32_bf16(A1,B1,acc,0,0,0);
      #pragma unroll
      for (int r=0;r<4;r++) os[(rowb+q*4+r)*LDO + nt*16 + mr] = f2b(acc[r]);
    }
    const int lr = lane>>2, cc = lane&3;
    const int tgt = prevP[sbase + rowb + lr];
    u16* gp = revOut + (size_t)tgt*D + cc*16;
    *(uint4*)gp     = *(const uint4*)&os[(rowb+lr)*LDO + cc*16];
    *(uint4*)(gp+8) = *(const uint4*)&os[(rowb+lr)*LDO + cc*16 + 8];
    // fused per-node reduction (wave-local os + nid); packed bf16 atomic flush
    float acc = 0.f;
    int curn = nid[rowb];
    #pragma unroll 4
    for (int i=0;i<16;++i){
      int n = nid[rowb+i];                 // wave-uniform
      if (n != curn){
        float hi = __shfl_xor(acc, 1, 64);
        if (!(lane&1)) atomic_pk_bf16(naWb_out + (size_t)curn*D + lane, acc, hi);
        curn = n; acc = 0.f;
      }
      acc += b2f(os[(rowb+i)*LDO + lane]);
    }
    float hi = __shfl_xor(acc, 1, 64);
    if (!(lane&1)) atomic_pk_bf16(naWb_out + (size_t)curn*D + lane, acc, hi);
  }
}

// ---------------- final BP step (barrier-free): e2n += per-node (fp32) ----------------
__global__ __launch_bounds__(256) void k_last(const u16* __restrict__ imP, const u16* __restrict__ revIn,
      const u16* __restrict__ naWb, const float* __restrict__ bc,
      const int* __restrict__ srcP, const int* __restrict__ nodeP,
      float* __restrict__ e2n){
  __shared__ __align__(16) u16 xs[64*LDW];
  __shared__ int nid[64];
  const int t = threadIdx.x;
  const int lane = t&63, w = t>>6;
  const size_t sbase = (size_t)blockIdx.x*64;
  if (lane < 16) nid[w*16+lane] = nodeP[sbase + w*16 + lane];   // wave-local
  {
    const int e = t>>2, d0 = (t&3)*16;
    const size_t slot = sbase + e;
    const u16* ip = imP + slot*D + d0;
    uint4 r0 = *(const uint4*)ip, r1 = *(const uint4*)(ip+8);
    float x[16]; unpack8(r0,x); unpack8(r1,x+8);
    const int sp = srcP[slot];
    const u16* cp = revIn + slot*D + d0;
    uint4 c0 = *(const uint4*)cp, c1 = *(const uint4*)(cp+8);
    const u16* np_ = naWb + (size_t)sp*D + d0;
    uint4 n0 = *(const uint4*)np_, n1 = *(const uint4*)(np_+8);
    float cv[16], nv[16];
    unpack8(c0,cv); unpack8(c1,cv+8);
    unpack8(n0,nv); unpack8(n1,nv+8);
    #pragma unroll
    for (int j=0;j<16;j++){ x[j] += nv[j] - cv[j] + bc[d0+j]; x[j] = x[j]>0.f ? x[j] : 0.f; }
    uint4 p0 = make_uint4(pack2(x[0],x[1]),pack2(x[2],x[3]),pack2(x[4],x[5]),pack2(x[6],x[7]));
    uint4 p1 = make_uint4(pack2(x[8],x[9]),pack2(x[10],x[11]),pack2(x[12],x[13]),pack2(x[14],x[15]));
    u16* qd = &xs[e*LDW + d0];
    *(uint4*)qd = p0; *(uint4*)(qd+8) = p1;
  }
  { // wave-local reduction, no barrier
    float acc = 0.f;
    int curn = nid[w*16];
    #pragma unroll 4
    for (int i=0;i<16;++i){
      int n = nid[w*16+i];
      if (n != curn){
        atomicAdd(&e2n[(size_t)curn*D + lane], acc);
        curn = n; acc = 0.f;
      }
      acc += b2f(xs[(w*16+i)*LDW + lane]);
    }
    atomicAdd(&e2n[(size_t)curn*D + lane], acc);
  }
}

// ---------------- CSR build ----------------
__global__ void k_hist(const int* __restrict__ dst, int* __restrict__ cnt){
  int e = blockIdx.x*256 + threadIdx.x;
  atomicAdd(&cnt[dst[e]], 1);
}
__global__ __launch_bounds__(1024) void k_scan1(const int* __restrict__ cnt, int* __restrict__ outv,
                                                int* __restrict__ bsums, int n){
  __shared__ int sh[1024];
  int i = blockIdx.x*1024 + threadIdx.x;
  int v = (i<n)? cnt[i] : 0;
  sh[threadIdx.x]=v;
  __syncthreads();
  for (int off=1; off<1024; off<<=1){
    int tv = (threadIdx.x>=(unsigned)off)? sh[threadIdx.x-off] : 0;
    __syncthreads();
    sh[threadIdx.x] += tv;
    __syncthreads();
  }
  if (i<n) outv[i] = sh[threadIdx.x] - v;
  if (threadIdx.x==1023) bsums[blockIdx.x] = sh[1023];
}
__global__ __launch_bounds__(1024) void k_scan3(int* __restrict__ off, int* __restrict__ cur,
                                                const int* __restrict__ bsums, int n){
  __shared__ int spref;
  if (threadIdx.x < 64){
    int v = ((int)threadIdx.x < (int)blockIdx.x) ? bsums[threadIdx.x] : 0;
    #pragma unroll
    for (int o=1;o<64;o<<=1) v += __shfl_xor(v, o, 64);
    if (threadIdx.x==0) spref = v;
  }
  __syncthreads();
  int i = blockIdx.x*1024 + threadIdx.x;
  if (i<n){ int v = off[i] + spref; off[i]=v; cur[i]=v; }
}
__global__ void k_fill(const int* __restrict__ dst, const int* __restrict__ src,
                       int* __restrict__ cur, int* __restrict__ perm,
                       int* __restrict__ srcP, int* __restrict__ nodeP){
  int e = blockIdx.x*256 + threadIdx.x;
  int d = dst[e];
  int pos = atomicAdd(&cur[d], 1);
  perm[e] = pos;
  srcP[pos] = src[e];
  nodeP[pos] = d;
}
__global__ void k_prev(const int* __restrict__ rev, const int* __restrict__ perm, int* __restrict__ prevP){
  int e = blockIdx.x*256 + threadIdx.x;
  prevP[perm[e]] = perm[rev[e]];
}

// ---------------- final: relu(e2n)@Wo+bo -> relu -> graph segsum ----------------
__global__ __launch_bounds__(256) void k_final(const float* __restrict__ e2n, const float* __restrict__ Wo,
                                               const float* __restrict__ bo, const int* __restrict__ gid,
                                               float* __restrict__ yacc){
  __shared__ float w[D*D];
  for (int i=threadIdx.x;i<D*D;i+=256) w[i]=Wo[i];
  __syncthreads();
  const int d = threadIdx.x&63, sub = threadIdx.x>>6;
  const int n0 = blockIdx.x*32 + sub*8;
  const float bod = bo[d];
  float acc=0.f; int curg=-1;
  for (int i=0;i<8;i++){
    int n=n0+i;
    if (n>=NN) break;
    int g = gid[n];
    if (g!=curg){ if (curg>=0) atomicAdd(&yacc[curg*D+d], acc); curg=g; acc=0.f; }
    float v=bod;
    const float* er = e2n + (size_t)n*D;
    #pragma unroll 8
    for (int k=0;k<D;k++){ float h=er[k]; h = h>0.f?h:0.f; v += h*w[k*D+d]; }
    acc += (v>0.f ? v : 0.f);
  }
  if (curg>=0) atomicAdd(&yacc[curg*D+d], acc);
}
__global__ void k_out(const float* __restrict__ yacc, float* __restrict__ outp){
  int i = blockIdx.x*256 + threadIdx.x;
  if (i<NG*D){ float v=yacc[i]; outp[i]= v>0.f?v:0.f; }
}

// ---------------- workspace layout ----------------
static constexpr size_t SZ_E   = (size_t)NE*D*2;          // 102.4 MB bf16 edge array
static constexpr size_t SZ_NF4 = (size_t)NN*D*4;          // 12.8 MB fp32 node array
static constexpr size_t SZ_NB  = (size_t)NN*D*2;          // 6.4 MB bf16 node array
static constexpr size_t OFF_IMP  = 0;
static constexpr size_t OFF_RVA  = SZ_E;
static constexpr size_t OFF_RVB  = 2*SZ_E;
// contiguous zero region: csr_cur | e2n | yacc | nb0 | nb1 | nb2
static constexpr size_t OFF_CCUR = 3*SZ_E;
static constexpr size_t OFF_E2N  = OFF_CCUR + 200064;
static constexpr size_t OFF_YACC = OFF_E2N + SZ_NF4;
static constexpr size_t OFF_NB0  = OFF_YACC + (size_t)NG*D*4;
static constexpr size_t OFF_NB1  = OFF_NB0 + SZ_NB;
static constexpr size_t OFF_NB2  = OFF_NB1 + SZ_NB;
static constexpr size_t ZERO_SZ  = 200064 + SZ_NF4 + (size_t)NG*D*4 + 3*SZ_NB;
static constexpr size_t OFF_INL  = OFF_NB2 + SZ_NB;
static constexpr size_t OFF_COFF = OFF_INL + SZ_NB;
static constexpr size_t OFF_PERM = OFF_COFF + 200064;
static constexpr size_t OFF_SRCP = OFF_PERM + (size_t)NE*4;
static constexpr size_t OFF_PRVP = OFF_SRCP + (size_t)NE*4;
static constexpr size_t OFF_NODP = OFF_PRVP + (size_t)NE*4;
static constexpr size_t OFF_BS   = OFF_NODP + (size_t)NE*4;
static constexpr size_t OFF_WCT  = OFF_BS + 256;               // wcB: 8192 B
static constexpr size_t OFF_WET  = OFF_WCT + 8192;             // weB: 4096 B

extern "C" void kernel_launch(void* const* d_in, const int* in_sizes, int n_in,
                              void* d_out, int out_size, void* d_ws, size_t ws_size,
                              hipStream_t stream) {
  const float* node_feat = (const float*)d_in[0];
  const float* edge_feat = (const float*)d_in[1];
  const int*   src       = (const int*)d_in[2];
  const int*   dst       = (const int*)d_in[3];
  const int*   rev       = (const int*)d_in[4];
  const int*   gid       = (const int*)d_in[5];
  const float* Wn = (const float*)d_in[7];
  const float* bn = (const float*)d_in[8];
  const float* We = (const float*)d_in[9];
  const float* be = (const float*)d_in[10];
  const float* Wc = (const float*)d_in[11];
  const float* bc = (const float*)d_in[12];
  const float* Wo = (const float*)d_in[13];
  const float* bo = (const float*)d_in[14];

  char* ws = (char*)d_ws;
  u16*   imP     = (u16*)(ws + OFF_IMP);
  u16*   revA    = (u16*)(ws + OFF_RVA);
  u16*   revB    = (u16*)(ws + OFF_RVB);
  float* e2n     = (float*)(ws + OFF_E2N);
  float* yacc    = (float*)(ws + OFF_YACC);
  u16*   nb0     = (u16*)(ws + OFF_NB0);
  u16*   nb1     = (u16*)(ws + OFF_NB1);
  u16*   nb2     = (u16*)(ws + OFF_NB2);
  u16*   inlb    = (u16*)(ws + OFF_INL);
  int*   csr_off = (int*)(ws + OFF_COFF);
  int*   csr_cur = (int*)(ws + OFF_CCUR);
  int*   perm    = (int*)(ws + OFF_PERM);
  int*   srcP    = (int*)(ws + OFF_SRCP);
  int*   prevP   = (int*)(ws + OFF_PRVP);
  int*   nodeP   = (int*)(ws + OFF_NODP);
  int*   bsums   = (int*)(ws + OFF_BS);
  u16*   wcB     = (u16*)(ws + OFF_WCT);
  u16*   weB     = (u16*)(ws + OFF_WET);

  // one upfront memset: csr_cur + e2n + yacc + nb0/nb1/nb2
  hipMemsetAsync(ws + OFF_CCUR, 0, ZERO_SZ, stream);

  // CSR build
  k_hist <<<NE/256, 256, 0, stream>>>(dst, csr_cur);
  k_scan1<<<49, 1024, 0, stream>>>(csr_cur, csr_off, bsums, NN);
  k_scan3<<<49, 1024, 0, stream>>>(csr_off, csr_cur, bsums, NN);
  k_fill <<<NE/256, 256, 0, stream>>>(dst, src, csr_cur, perm, srcP, nodeP);
  k_prev <<<NE/256, 256, 0, stream>>>(rev, perm, prevP);

  // weights prep + front end
  k_prep<<<24, 256, 0, stream>>>(Wc, We, wcB, weB);
  k_inl <<<NN/4, 256, 0, stream>>>(node_feat, Wn, bn, inlb);
  k_im  <<<NE/64, 256, 0, stream>>>(edge_feat, weB, be, inlb, src, perm, imP);

  // loopy BP: direct packed-bf16 accumulation, triple-buffered naWb
  k_iter<0><<<NE/64, 256, 0, stream>>>(imP, revA, nb0, wcB, bc, srcP, prevP, nodeP, revA, nb0);
  k_iter<1><<<NE/64, 256, 0, stream>>>(imP, revA, nb0, wcB, bc, srcP, prevP, nodeP, revB, nb1);
  k_iter<1><<<NE/64, 256, 0, stream>>>(imP, revB, nb1, wcB, bc, srcP, prevP, nodeP, revA, nb2);
  k_last<<<NE/64, 256, 0, stream>>>(imP, revA, nb2, bc, srcP, nodeP, e2n);

  // head
  k_final<<<(NN+31)/32, 256, 0, stream>>>(e2n, Wo, bo, gid, yacc);
  k_out<<<(NG*D)/256, 256, 0, stream>>>(yacc, (float*)d_out);
}

// Round 10
// 613.213 us; speedup vs baseline: 1.2807x; 1.0590x over previous
//
#include <hip/hip_runtime.h>

// EmbedLoopyBP on gfx950 — round 18.
// R17 (649us) hot loop untouched. Tail optimized with the two levers R17
// proved: (1) pk-bf16 atomics: k_last now accumulates into bf16 e2nb
// (halved atomic ops + 6.4MB vs 12.8MB traffic); (2) MFMA everywhere:
// k_final rewritten in the k_iter phase-1/phase-2 pattern (relu(e2nb)@Wo
// via fragment-order woB + sorted-run gid reduction); (3) k_prep+k_inl+
// k_hist merged into k_pi0 (block-range split, shown neutral in R15 ledger).
// 15 -> 13 dispatches.

#define NN 50000
#define NE 800000
#define NG 128
#define D 64
#define LDE 36
#define LDW 66
#define LDO 72

typedef unsigned short u16;
typedef unsigned int u32;
typedef __bf16 bf16x8 __attribute__((ext_vector_type(8)));
typedef float f32x4 __attribute__((ext_vector_type(4)));
typedef short s16x2 __attribute__((ext_vector_type(2)));

__device__ __forceinline__ float b2f(u16 u){ u32 x=((u32)u)<<16; float f; __builtin_memcpy(&f,&x,4); return f; }
__device__ __forceinline__ u16 f2b(float f){ u32 x; __builtin_memcpy(&x,&f,4); x += 0x7fffu + ((x>>16)&1u); return (u16)(x>>16); }
__device__ __forceinline__ u32 pack2(float a, float b){ return (u32)f2b(a) | ((u32)f2b(b)<<16); }
__device__ __forceinline__ void unpack8(uint4 v, float* o){
  o[0]=b2f((u16)(v.x&0xffffu)); o[1]=b2f((u16)(v.x>>16));
  o[2]=b2f((u16)(v.y&0xffffu)); o[3]=b2f((u16)(v.y>>16));
  o[4]=b2f((u16)(v.z&0xffffu)); o[5]=b2f((u16)(v.z>>16));
  o[6]=b2f((u16)(v.w&0xffffu)); o[7]=b2f((u16)(v.w>>16));
}
// packed bf16 atomic add of (lo,hi) at u16-address addr (4B-aligned)
__device__ __forceinline__ void atomic_pk_bf16(u16* addr, float lo, float hi){
  s16x2 v; v.x = (short)f2b(lo); v.y = (short)f2b(hi);
  __builtin_amdgcn_global_atomic_fadd_v2bf16((s16x2*)addr, v);
}

// ---------------- merged: node linear + weight fragment builds + dst histogram ----------------
// blocks [0,12500):       inlb = bf16(node_feat @ Wn + bn)
// blocks [12500,12540):   wcB/weB/woB fragment-order build (10240 elems)
// blocks [12540,15665):   histogram of dst into csr_cur
// wcB/woB[nt][h][j][kk]: lane j's B fragment for tile nt, K-half h at
//   base+nt*1024+h*512+j*8; j=q*16+mr; elem kk -> W[(h*32+q*8+kk)*D + nt*16+mr]
// weB[nt][j][kk]: K=32, elem kk -> We[(q*8+kk)*D + nt*16+mr]
__global__ __launch_bounds__(256) void k_pi0(const float* __restrict__ nf, const float* __restrict__ Wn,
                                             const float* __restrict__ bn, const float* __restrict__ Wc,
                                             const float* __restrict__ We, const float* __restrict__ Wo,
                                             const int* __restrict__ dst,
                                             u16* __restrict__ inlb, u16* __restrict__ wcB,
                                             u16* __restrict__ weB, u16* __restrict__ woB,
                                             int* __restrict__ cnt){
  const int bid = blockIdx.x;
  if (bid >= 12540){           // histogram
    int e = (bid - 12540)*256 + threadIdx.x;
    atomicAdd(&cnt[dst[e]], 1);
    return;
  }
  if (bid >= 12500){           // weight fragment builds
    int i = (bid - 12500)*256 + threadIdx.x;
    if (i < 4096){
      int nt = i>>10, r = i&1023;
      int h = r>>9, r2 = r&511;
      int j = r2>>3, kk = r2&7;
      int row = nt*16 + (j&15);
      int k = h*32 + (j>>4)*8 + kk;
      wcB[i] = f2b(Wc[k*D + row]);
    } else if (i < 6144){
      int t = i - 4096;
      int nt = t>>9, r = t&511;
      int j = r>>3, kk = r&7;
      int row = nt*16 + (j&15);
      int k = (j>>4)*8 + kk;
      weB[t] = f2b(We[k*D + row]);
    } else if (i < 10240){
      int t = i - 6144;
      int nt = t>>10, r = t&1023;
      int h = r>>9, r2 = r&511;
      int j = r2>>3, kk = r2&7;
      int row = nt*16 + (j&15);
      int k = h*32 + (j>>4)*8 + kk;
      woB[t] = f2b(Wo[k*D + row]);
    }
    return;
  }
  __shared__ float w[D*D];     // node linear
  for (int i=threadIdx.x;i<D*D;i+=256) w[i]=Wn[i];
  __syncthreads();
  const int d = threadIdx.x&63;
  const int n = bid*4 + (threadIdx.x>>6);
  float v = bn[d];
  const float* row = nf + (size_t)n*D;
  #pragma unroll 8
  for (int k=0;k<D;k++) v += row[k]*w[k*D+d];
  inlb[(size_t)n*D+d] = f2b(v);
}

// ---------------- imP[perm[e]] = edge_feat@We + be + inl[src[e]]  (bf16) ----------------
// barrier-free: efs/os rows wave-local; B from global weB (L1-hot)
__global__ __launch_bounds__(256) void k_im(const float* __restrict__ ef, const u16* __restrict__ weB,
                                            const float* __restrict__ be, const u16* __restrict__ inlb,
                                            const int* __restrict__ src, const int* __restrict__ perm,
                                            u16* __restrict__ imP){
  __shared__ __align__(16) u16 efs[64*LDE];
  __shared__ float os[64*68];
  const int t = threadIdx.x;
  const int ebase = blockIdx.x*64;
  { // stage edge_feat bf16 (coalesced float4 reads); wave-local rows
    int e=t>>2, k0=(t&3)*8;
    const float* p = ef + (size_t)(ebase+e)*32 + k0;
    float4 v0=*(const float4*)p, v1=*(const float4*)(p+4);
    uint4 pk = make_uint4(pack2(v0.x,v0.y),pack2(v0.z,v0.w),pack2(v1.x,v1.y),pack2(v1.z,v1.w));
    *(uint4*)&efs[e*LDE + k0] = pk;
  }
  { // MFMA 16x16x32 (K=32, one step); B fragments from global, coalesced
    int w=t>>6, lane=t&63, q=lane>>4, mr=lane&15;
    int rowb=w*16;
    bf16x8 A = *(const bf16x8*)&efs[(rowb+mr)*LDE + q*8];
    #pragma unroll
    for (int nt=0;nt<4;nt++){
      bf16x8 B = *(const bf16x8*)(weB + nt*512 + lane*8);
      f32x4 acc = {0.f,0.f,0.f,0.f};
      acc = __builtin_amdgcn_mfma_f32_16x16x32_bf16(A,B,acc,0,0,0);
      #pragma unroll
      for (int r=0;r<4;r++) os[(rowb+q*4+r)*68 + nt*16+mr] = acc[r];
    }
  }
  { // epilogue: + be + inlb[src[e]] -> bf16, full-row scatter to imP[perm[e]]
    int e=t>>2, d0=(t&3)*16;
    const size_t eg = (size_t)(ebase+e);
    const int s = src[eg], ps = perm[eg];
    const u16* ip = inlb + (size_t)s*D + d0;
    uint4 iv0 = *(const uint4*)ip, iv1 = *(const uint4*)(ip+8);
    float il[16]; unpack8(iv0,il); unpack8(iv1,il+8);
    float x[16];
    #pragma unroll
    for (int j=0;j<16;j++) x[j] = os[e*68 + d0 + j] + be[d0+j] + il[j];
    uint4 p0 = make_uint4(pack2(x[0],x[1]),pack2(x[2],x[3]),pack2(x[4],x[5]),pack2(x[6],x[7]));
    uint4 p1 = make_uint4(pack2(x[8],x[9]),pack2(x[10],x[11]),pack2(x[12],x[13]),pack2(x[14],x[15]));
    u16* op = imP + (size_t)ps*D + d0;
    *(uint4*)op = p0; *(uint4*)(op+8) = p1;
  }
}

// ---------------- iteration kernel: 64 slots/block, ZERO barriers ----------------
// MODE 0: x=relu(imP[slot]);                                revOut[prevP[slot]]=(x@Wc); naWb_out += per-node (pk bf16)
// MODE 1: x=relu(naWb[srcP] (bf16) - revIn[slot]+bc+imP[slot]); same outputs
template<int MODE>
__global__ __launch_bounds__(256) void k_iter(const u16* __restrict__ imP, const u16* __restrict__ revIn,
      const u16* __restrict__ naWb, const u16* __restrict__ wcB, const float* __restrict__ bc,
      const int* __restrict__ srcP, const int* __restrict__ prevP, const int* __restrict__ nodeP,
      u16* __restrict__ revOut, u16* __restrict__ naWb_out){
  __shared__ __align__(16) u16 xs[64*LDW];
  __shared__ __align__(16) u16 os[64*LDO];
  __shared__ int nid[64];
  const int t = threadIdx.x;
  const int lane = t&63, w = t>>6;
  const size_t sbase = (size_t)blockIdx.x*64;
  if (lane < 16) nid[w*16 + lane] = nodeP[sbase + w*16 + lane];   // wave-local
  { // phase 1: stream reads + bf16 naWb row gather; xs rows wave-local
    const int e = t>>2, d0 = (t&3)*16;
    const size_t slot = sbase + e;
    const u16* ip = imP + slot*D + d0;
    uint4 r0 = *(const uint4*)ip, r1 = *(const uint4*)(ip+8);
    float x[16]; unpack8(r0,x); unpack8(r1,x+8);
    if (MODE == 1){
      const int sp = srcP[slot];
      const u16* cp = revIn + slot*D + d0;
      uint4 c0=*(const uint4*)cp, c1=*(const uint4*)(cp+8);
      const u16* np_ = naWb + (size_t)sp*D + d0;
      uint4 n0=*(const uint4*)np_, n1=*(const uint4*)(np_+8);
      float cv[16], nv[16];
      unpack8(c0,cv); unpack8(c1,cv+8);
      unpack8(n0,nv); unpack8(n1,nv+8);
      #pragma unroll
      for (int j=0;j<16;j++) x[j] += nv[j] - cv[j] + bc[d0+j];
    }
    #pragma unroll
    for (int j=0;j<16;j++) x[j] = x[j]>0.f ? x[j] : 0.f;
    uint4 p0 = make_uint4(pack2(x[0],x[1]),pack2(x[2],x[3]),pack2(x[4],x[5]),pack2(x[6],x[7]));
    uint4 p1 = make_uint4(pack2(x[8],x[9]),pack2(x[10],x[11]),pack2(x[12],x[13]),pack2(x[14],x[15]));
    u16* qd = &xs[e*LDW + d0];
    *(uint4*)qd = p0; *(uint4*)(qd+8) = p1;
  }
  { // phase 2: MFMA (xs wave-local, no barrier); scatter store + fused flush
    const int q = lane>>4, mr = lane&15;
    const int rowb = w*16;
    bf16x8 A0 = *(const bf16x8*)&xs[(rowb+mr)*LDW + q*8];
    bf16x8 A1 = *(const bf16x8*)&xs[(rowb+mr)*LDW + 32 + q*8];
    #pragma unroll
    for (int nt=0;nt<4;nt++){
      bf16x8 B0 = *(const bf16x8*)(wcB + nt*1024 + lane*8);
      bf16x8 B1 = *(const bf16x8*)(wcB + nt*1024 + 512 + lane*8);
      f32x4 acc = {0.f,0.f,0.f,0.f};
      acc = __builtin_amdgcn_mfma_f32_16x16x32_bf16(A0,B0,acc,0,0,0);
      acc = __builtin_amdgcn_mfma_f32_16x16x32_bf16(A1,B1,acc,0,0,0);
      #pragma unroll
      for (int r=0;r<4;r++) os[(rowb+q*4+r)*LDO + nt*16 + mr] = f2b(acc[r]);
    }
    const int lr = lane>>2, cc = lane&3;
    const int tgt = prevP[sbase + rowb + lr];
    u16* gp = revOut + (size_t)tgt*D + cc*16;
    *(uint4*)gp     = *(const uint4*)&os[(rowb+lr)*LDO + cc*16];
    *(uint4*)(gp+8) = *(const uint4*)&os[(rowb+lr)*LDO + cc*16 + 8];
    // fused per-node reduction (wave-local os + nid); packed bf16 atomic flush
    float acc = 0.f;
    int curn = nid[rowb];
    #pragma unroll 4
    for (int i=0;i<16;++i){
      int n = nid[rowb+i];                 // wave-uniform
      if (n != curn){
        float hi = __shfl_xor(acc, 1, 64);
        if (!(lane&1)) atomic_pk_bf16(naWb_out + (size_t)curn*D + lane, acc, hi);
        curn = n; acc = 0.f;
      }
      acc += b2f(os[(rowb+i)*LDO + lane]);
    }
    float hi = __shfl_xor(acc, 1, 64);
    if (!(lane&1)) atomic_pk_bf16(naWb_out + (size_t)curn*D + lane, acc, hi);
  }
}

// ---------------- final BP step (barrier-free): e2nb += per-node (pk bf16) ----------------
__global__ __launch_bounds__(256) void k_last(const u16* __restrict__ imP, const u16* __restrict__ revIn,
      const u16* __restrict__ naWb, const float* __restrict__ bc,
      const int* __restrict__ srcP, const int* __restrict__ nodeP,
      u16* __restrict__ e2nb){
  __shared__ __align__(16) u16 xs[64*LDW];
  __shared__ int nid[64];
  const int t = threadIdx.x;
  const int lane = t&63, w = t>>6;
  const size_t sbase = (size_t)blockIdx.x*64;
  if (lane < 16) nid[w*16+lane] = nodeP[sbase + w*16 + lane];   // wave-local
  {
    const int e = t>>2, d0 = (t&3)*16;
    const size_t slot = sbase + e;
    const u16* ip = imP + slot*D + d0;
    uint4 r0 = *(const uint4*)ip, r1 = *(const uint4*)(ip+8);
    float x[16]; unpack8(r0,x); unpack8(r1,x+8);
    const int sp = srcP[slot];
    const u16* cp = revIn + slot*D + d0;
    uint4 c0 = *(const uint4*)cp, c1 = *(const uint4*)(cp+8);
    const u16* np_ = naWb + (size_t)sp*D + d0;
    uint4 n0 = *(const uint4*)np_, n1 = *(const uint4*)(np_+8);
    float cv[16], nv[16];
    unpack8(c0,cv); unpack8(c1,cv+8);
    unpack8(n0,nv); unpack8(n1,nv+8);
    #pragma unroll
    for (int j=0;j<16;j++){ x[j] += nv[j] - cv[j] + bc[d0+j]; x[j] = x[j]>0.f ? x[j] : 0.f; }
    uint4 p0 = make_uint4(pack2(x[0],x[1]),pack2(x[2],x[3]),pack2(x[4],x[5]),pack2(x[6],x[7]));
    uint4 p1 = make_uint4(pack2(x[8],x[9]),pack2(x[10],x[11]),pack2(x[12],x[13]),pack2(x[14],x[15]));
    u16* qd = &xs[e*LDW + d0];
    *(uint4*)qd = p0; *(uint4*)(qd+8) = p1;
  }
  { // wave-local reduction; packed bf16 atomic flush
    float acc = 0.f;
    int curn = nid[w*16];
    #pragma unroll 4
    for (int i=0;i<16;++i){
      int n = nid[w*16+i];
      if (n != curn){
        float hi = __shfl_xor(acc, 1, 64);
        if (!(lane&1)) atomic_pk_bf16(e2nb + (size_t)curn*D + lane, acc, hi);
        curn = n; acc = 0.f;
      }
      acc += b2f(xs[(w*16+i)*LDW + lane]);
    }
    float hi = __shfl_xor(acc, 1, 64);
    if (!(lane&1)) atomic_pk_bf16(e2nb + (size_t)curn*D + lane, acc, hi);
  }
}

// ---------------- CSR build ----------------
__global__ __launch_bounds__(1024) void k_scan1(const int* __restrict__ cnt, int* __restrict__ outv,
                                                int* __restrict__ bsums, int n){
  __shared__ int sh[1024];
  int i = blockIdx.x*1024 + threadIdx.x;
  int v = (i<n)? cnt[i] : 0;
  sh[threadIdx.x]=v;
  __syncthreads();
  for (int off=1; off<1024; off<<=1){
    int tv = (threadIdx.x>=(unsigned)off)? sh[threadIdx.x-off] : 0;
    __syncthreads();
    sh[threadIdx.x] += tv;
    __syncthreads();
  }
  if (i<n) outv[i] = sh[threadIdx.x] - v;
  if (threadIdx.x==1023) bsums[blockIdx.x] = sh[1023];
}
__global__ __launch_bounds__(1024) void k_scan3(int* __restrict__ off, int* __restrict__ cur,
                                                const int* __restrict__ bsums, int n){
  __shared__ int spref;
  if (threadIdx.x < 64){
    int v = ((int)threadIdx.x < (int)blockIdx.x) ? bsums[threadIdx.x] : 0;
    #pragma unroll
    for (int o=1;o<64;o<<=1) v += __shfl_xor(v, o, 64);
    if (threadIdx.x==0) spref = v;
  }
  __syncthreads();
  int i = blockIdx.x*1024 + threadIdx.x;
  if (i<n){ int v = off[i] + spref; off[i]=v; cur[i]=v; }
}
__global__ void k_fill(const int* __restrict__ dst, const int* __restrict__ src,
                       int* __restrict__ cur, int* __restrict__ perm,
                       int* __restrict__ srcP, int* __restrict__ nodeP){
  int e = blockIdx.x*256 + threadIdx.x;
  int d = dst[e];
  int pos = atomicAdd(&cur[d], 1);
  perm[e] = pos;
  srcP[pos] = src[e];
  nodeP[pos] = d;
}
__global__ void k_prev(const int* __restrict__ rev, const int* __restrict__ perm, int* __restrict__ prevP){
  int e = blockIdx.x*256 + threadIdx.x;
  prevP[perm[e]] = perm[rev[e]];
}

// ---------------- MFMA final: relu(e2nb)@Wo, +bo, relu, gid run-reduction -> yacc ----------------
__global__ __launch_bounds__(256) void k_finalM(const u16* __restrict__ e2nb, const u16* __restrict__ woB,
                                                const float* __restrict__ bo, const int* __restrict__ gid,
                                                float* __restrict__ yacc){
  __shared__ __align__(16) u16 xs[64*LDW];
  __shared__ float os[64*68];
  __shared__ int gidS[64];
  const int t = threadIdx.x;
  const int lane = t&63, w = t>>6;
  const int nbase = blockIdx.x*64;
  if (lane < 16){
    int n = nbase + w*16 + lane;
    gidS[w*16 + lane] = (n < NN) ? gid[n] : -1;      // wave-local
  }
  { // phase 1: load e2nb row, relu -> xs (zeros for padded nodes)
    const int e = t>>2, d0 = (t&3)*16;
    const int n = nbase + e;
    float x[16];
    if (n < NN){
      const u16* ip = e2nb + (size_t)n*D + d0;
      uint4 r0 = *(const uint4*)ip, r1 = *(const uint4*)(ip+8);
      unpack8(r0,x); unpack8(r1,x+8);
      #pragma unroll
      for (int j=0;j<16;j++) x[j] = x[j]>0.f ? x[j] : 0.f;
    } else {
      #pragma unroll
      for (int j=0;j<16;j++) x[j] = 0.f;
    }
    uint4 p0 = make_uint4(pack2(x[0],x[1]),pack2(x[2],x[3]),pack2(x[4],x[5]),pack2(x[6],x[7]));
    uint4 p1 = make_uint4(pack2(x[8],x[9]),pack2(x[10],x[11]),pack2(x[12],x[13]),pack2(x[14],x[15]));
    u16* qd = &xs[e*LDW + d0];
    *(uint4*)qd = p0; *(uint4*)(qd+8) = p1;
  }
  { // phase 2: MFMA xs@Wo (K=64) -> os fp32; +bo,relu inside run-reduction
    const int q = lane>>4, mr = lane&15;
    const int rowb = w*16;
    bf16x8 A0 = *(const bf16x8*)&xs[(rowb+mr)*LDW + q*8];
    bf16x8 A1 = *(const bf16x8*)&xs[(rowb+mr)*LDW + 32 + q*8];
    #pragma unroll
    for (int nt=0;nt<4;nt++){
      bf16x8 B0 = *(const bf16x8*)(woB + nt*1024 + lane*8);
      bf16x8 B1 = *(const bf16x8*)(woB + nt*1024 + 512 + lane*8);
      f32x4 acc = {0.f,0.f,0.f,0.f};
      acc = __builtin_amdgcn_mfma_f32_16x16x32_bf16(A0,B0,acc,0,0,0);
      acc = __builtin_amdgcn_mfma_f32_16x16x32_bf16(A1,B1,acc,0,0,0);
      #pragma unroll
      for (int r=0;r<4;r++) os[(rowb+q*4+r)*68 + nt*16 + mr] = acc[r];
    }
    const float bol = bo[lane];
    float acc = 0.f;
    int curg = gidS[rowb];
    #pragma unroll 4
    for (int i=0;i<16;++i){
      int g = gidS[rowb+i];                // wave-uniform
      if (g != curg){
        if (curg >= 0) atomicAdd(&yacc[curg*D + lane], acc);
        curg = g; acc = 0.f;
      }
      if (g >= 0){
        float v = os[(rowb+i)*68 + lane] + bol;
        acc += v>0.f ? v : 0.f;
      }
    }
    if (curg >= 0) atomicAdd(&yacc[curg*D + lane], acc);
  }
}
__global__ void k_out(const float* __restrict__ yacc, float* __restrict__ outp){
  int i = blockIdx.x*256 + threadIdx.x;
  if (i<NG*D){ float v=yacc[i]; outp[i]= v>0.f?v:0.f; }
}

// ---------------- workspace layout ----------------
static constexpr size_t SZ_E   = (size_t)NE*D*2;          // 102.4 MB bf16 edge array
static constexpr size_t SZ_NB  = (size_t)NN*D*2;          // 6.4 MB bf16 node array
static constexpr size_t OFF_IMP  = 0;
static constexpr size_t OFF_RVA  = SZ_E;
static constexpr size_t OFF_RVB  = 2*SZ_E;
// contiguous zero region: csr_cur | yacc | nb0 | nb1 | nb2 | e2nb
static constexpr size_t OFF_CCUR = 3*SZ_E;
static constexpr size_t OFF_YACC = OFF_CCUR + 200064;
static constexpr size_t OFF_NB0  = OFF_YACC + (size_t)NG*D*4;
static constexpr size_t OFF_NB1  = OFF_NB0 + SZ_NB;
static constexpr size_t OFF_NB2  = OFF_NB1 + SZ_NB;
static constexpr size_t OFF_E2NB = OFF_NB2 + SZ_NB;
static constexpr size_t ZERO_SZ  = 200064 + (size_t)NG*D*4 + 4*SZ_NB;
static constexpr size_t OFF_INL  = OFF_E2NB + SZ_NB;
static constexpr size_t OFF_COFF = OFF_INL + SZ_NB;
static constexpr size_t OFF_PERM = OFF_COFF + 200064;
static constexpr size_t OFF_SRCP = OFF_PERM + (size_t)NE*4;
static constexpr size_t OFF_PRVP = OFF_SRCP + (size_t)NE*4;
static constexpr size_t OFF_NODP = OFF_PRVP + (size_t)NE*4;
static constexpr size_t OFF_BS   = OFF_NODP + (size_t)NE*4;
static constexpr size_t OFF_WCT  = OFF_BS + 256;               // wcB: 8192 B
static constexpr size_t OFF_WET  = OFF_WCT + 8192;             // weB: 4096 B
static constexpr size_t OFF_WOT  = OFF_WET + 4096;             // woB: 8192 B

extern "C" void kernel_launch(void* const* d_in, const int* in_sizes, int n_in,
                              void* d_out, int out_size, void* d_ws, size_t ws_size,
                              hipStream_t stream) {
  const float* node_feat = (const float*)d_in[0];
  const float* edge_feat = (const float*)d_in[1];
  const int*   src       = (const int*)d_in[2];
  const int*   dst       = (const int*)d_in[3];
  const int*   rev       = (const int*)d_in[4];
  const int*   gid       = (const int*)d_in[5];
  const float* Wn = (const float*)d_in[7];
  const float* bn = (const float*)d_in[8];
  const float* We = (const float*)d_in[9];
  const float* be = (const float*)d_in[10];
  const float* Wc = (const float*)d_in[11];
  const float* bc = (const float*)d_in[12];
  const float* Wo = (const float*)d_in[13];
  const float* bo = (const float*)d_in[14];

  char* ws = (char*)d_ws;
  u16*   imP     = (u16*)(ws + OFF_IMP);
  u16*   revA    = (u16*)(ws + OFF_RVA);
  u16*   revB    = (u16*)(ws + OFF_RVB);
  float* yacc    = (float*)(ws + OFF_YACC);
  u16*   nb0     = (u16*)(ws + OFF_NB0);
  u16*   nb1     = (u16*)(ws + OFF_NB1);
  u16*   nb2     = (u16*)(ws + OFF_NB2);
  u16*   e2nb    = (u16*)(ws + OFF_E2NB);
  u16*   inlb    = (u16*)(ws + OFF_INL);
  int*   csr_off = (int*)(ws + OFF_COFF);
  int*   csr_cur = (int*)(ws + OFF_CCUR);
  int*   perm    = (int*)(ws + OFF_PERM);
  int*   srcP    = (int*)(ws + OFF_SRCP);
  int*   prevP   = (int*)(ws + OFF_PRVP);
  int*   nodeP   = (int*)(ws + OFF_NODP);
  int*   bsums   = (int*)(ws + OFF_BS);
  u16*   wcB     = (u16*)(ws + OFF_WCT);
  u16*   weB     = (u16*)(ws + OFF_WET);
  u16*   woB     = (u16*)(ws + OFF_WOT);

  // one upfront memset: csr_cur + yacc + nb0/nb1/nb2 + e2nb
  hipMemsetAsync(ws + OFF_CCUR, 0, ZERO_SZ, stream);

  // merged: node linear + weight fragments + dst histogram
  k_pi0<<<15665, 256, 0, stream>>>(node_feat, Wn, bn, Wc, We, Wo, dst, inlb, wcB, weB, woB, csr_cur);

  // CSR build
  k_scan1<<<49, 1024, 0, stream>>>(csr_cur, csr_off, bsums, NN);
  k_scan3<<<49, 1024, 0, stream>>>(csr_off, csr_cur, bsums, NN);
  k_fill <<<NE/256, 256, 0, stream>>>(dst, src, csr_cur, perm, srcP, nodeP);
  k_prev <<<NE/256, 256, 0, stream>>>(rev, perm, prevP);

  // front end
  k_im  <<<NE/64, 256, 0, stream>>>(edge_feat, weB, be, inlb, src, perm, imP);

  // loopy BP: direct packed-bf16 accumulation, triple-buffered naWb
  k_iter<0><<<NE/64, 256, 0, stream>>>(imP, revA, nb0, wcB, bc, srcP, prevP, nodeP, revA, nb0);
  k_iter<1><<<NE/64, 256, 0, stream>>>(imP, revA, nb0, wcB, bc, srcP, prevP, nodeP, revB, nb1);
  k_iter<1><<<NE/64, 256, 0, stream>>>(imP, revB, nb1, wcB, bc, srcP, prevP, nodeP, revA, nb2);
  k_last<<<NE/64, 256, 0, stream>>>(imP, revA, nb2, bc, srcP, nodeP, e2nb);

  // head (MFMA final + out)
  k_finalM<<<(NN+63)/64, 256, 0, stream>>>(e2nb, woB, bo, gid, yacc);
  k_out<<<(NG*D)/256, 256, 0, stream>>>(yacc, (float*)d_out);
}

// Round 11
// 577.688 us; speedup vs baseline: 1.3595x; 1.0615x over previous
//
#include <hip/hip_runtime.h>

// EmbedLoopyBP on gfx950 — round 19.
// R18 (613us) with ONE isolated change: the twin-exchange rev buffers are
// fp8-e4m3 (software cvt, FTZ below 2^-6, clamp 448). Encode happens ONLY
// at the scatter write (os stays bf16 -> per-node agg path identical to
// R18). Decode at phase-1 read. revA/revB 102.4 -> 51.2 MB each; BP-loop
// working set ~224MB < 256MB L3. All other kernels byte-identical to R18.
// Revert criterion: accuracy fail -> back to R18, declare roofline.

#define NN 50000
#define NE 800000
#define NG 128
#define D 64
#define LDE 36
#define LDW 66
#define LDO 72

typedef unsigned short u16;
typedef unsigned char u8;
typedef unsigned int u32;
typedef __bf16 bf16x8 __attribute__((ext_vector_type(8)));
typedef float f32x4 __attribute__((ext_vector_type(4)));
typedef short s16x2 __attribute__((ext_vector_type(2)));

__device__ __forceinline__ float b2f(u16 u){ u32 x=((u32)u)<<16; float f; __builtin_memcpy(&f,&x,4); return f; }
__device__ __forceinline__ u16 f2b(float f){ u32 x; __builtin_memcpy(&x,&f,4); x += 0x7fffu + ((x>>16)&1u); return (u16)(x>>16); }
__device__ __forceinline__ u32 pack2(float a, float b){ return (u32)f2b(a) | ((u32)f2b(b)<<16); }
__device__ __forceinline__ void unpack8(uint4 v, float* o){
  o[0]=b2f((u16)(v.x&0xffffu)); o[1]=b2f((u16)(v.x>>16));
  o[2]=b2f((u16)(v.y&0xffffu)); o[3]=b2f((u16)(v.y>>16));
  o[4]=b2f((u16)(v.z&0xffffu)); o[5]=b2f((u16)(v.z>>16));
  o[6]=b2f((u16)(v.w&0xffffu)); o[7]=b2f((u16)(v.w>>16));
}
// packed bf16 atomic add of (lo,hi) at u16-address addr (4B-aligned)
__device__ __forceinline__ void atomic_pk_bf16(u16* addr, float lo, float hi){
  s16x2 v; v.x = (short)f2b(lo); v.y = (short)f2b(hi);
  __builtin_amdgcn_global_atomic_fadd_v2bf16((s16x2*)addr, v);
}
// ---- fp8 e4m3fn software cvt (RNE, FTZ below 2^-6, clamp 448) ----
__device__ __forceinline__ u32 f2e4m3_4(const float* x){   // 4 floats -> 4 fp8 bytes
  u32 out = 0;
  #pragma unroll
  for (int i=0;i<4;i++){
    u32 u; __builtin_memcpy(&u,&x[i],4);
    u32 s = (u>>24)&0x80u;
    u32 m = u&0x7fffffffu;
    m += 0x7ffffu + ((m>>20)&1u);          // RNE at mantissa bit 20
    if (m > 0x43e00000u) m = 0x43e00000u;  // clamp |x| to 448
    int e = (int)(m>>23) - 120;            // e4m3 field = exp8-127+7
    u32 r = (e<=0) ? 0u : (((u32)e<<3)|((m>>20)&7u));
    out |= ((s|r)&0xffu)<<(i*8);
  }
  return out;
}
__device__ __forceinline__ void e4m3_4f(u32 p, float* o){  // 4 fp8 bytes -> 4 floats
  #pragma unroll
  for (int i=0;i<4;i++){
    u32 v = (p>>(i*8))&0xffu;
    u32 s = (v&0x80u)<<24;
    u32 em = v&0x7fu;
    u32 u = (em>=8u) ? (s | (((em>>3)+120u)<<23) | ((em&7u)<<20)) : s;
    float f; __builtin_memcpy(&f,&u,4);
    o[i] = f;
  }
}
__device__ __forceinline__ void dec16(uint4 c, float* o){
  e4m3_4f(c.x,o); e4m3_4f(c.y,o+4); e4m3_4f(c.z,o+8); e4m3_4f(c.w,o+12);
}

// ---------------- merged: node linear + weight fragment builds + dst histogram ----------------
// blocks [0,12500):       inlb = bf16(node_feat @ Wn + bn)
// blocks [12500,12540):   wcB/weB/woB fragment-order build (10240 elems)
// blocks [12540,15665):   histogram of dst into csr_cur
__global__ __launch_bounds__(256) void k_pi0(const float* __restrict__ nf, const float* __restrict__ Wn,
                                             const float* __restrict__ bn, const float* __restrict__ Wc,
                                             const float* __restrict__ We, const float* __restrict__ Wo,
                                             const int* __restrict__ dst,
                                             u16* __restrict__ inlb, u16* __restrict__ wcB,
                                             u16* __restrict__ weB, u16* __restrict__ woB,
                                             int* __restrict__ cnt){
  const int bid = blockIdx.x;
  if (bid >= 12540){           // histogram
    int e = (bid - 12540)*256 + threadIdx.x;
    atomicAdd(&cnt[dst[e]], 1);
    return;
  }
  if (bid >= 12500){           // weight fragment builds
    int i = (bid - 12500)*256 + threadIdx.x;
    if (i < 4096){
      int nt = i>>10, r = i&1023;
      int h = r>>9, r2 = r&511;
      int j = r2>>3, kk = r2&7;
      int row = nt*16 + (j&15);
      int k = h*32 + (j>>4)*8 + kk;
      wcB[i] = f2b(Wc[k*D + row]);
    } else if (i < 6144){
      int t = i - 4096;
      int nt = t>>9, r = t&511;
      int j = r>>3, kk = r&7;
      int row = nt*16 + (j&15);
      int k = (j>>4)*8 + kk;
      weB[t] = f2b(We[k*D + row]);
    } else if (i < 10240){
      int t = i - 6144;
      int nt = t>>10, r = t&1023;
      int h = r>>9, r2 = r&511;
      int j = r2>>3, kk = r2&7;
      int row = nt*16 + (j&15);
      int k = h*32 + (j>>4)*8 + kk;
      woB[t] = f2b(Wo[k*D + row]);
    }
    return;
  }
  __shared__ float w[D*D];     // node linear
  for (int i=threadIdx.x;i<D*D;i+=256) w[i]=Wn[i];
  __syncthreads();
  const int d = threadIdx.x&63;
  const int n = bid*4 + (threadIdx.x>>6);
  float v = bn[d];
  const float* row = nf + (size_t)n*D;
  #pragma unroll 8
  for (int k=0;k<D;k++) v += row[k]*w[k*D+d];
  inlb[(size_t)n*D+d] = f2b(v);
}

// ---------------- imP[perm[e]] = edge_feat@We + be + inl[src[e]]  (bf16) ----------------
__global__ __launch_bounds__(256) void k_im(const float* __restrict__ ef, const u16* __restrict__ weB,
                                            const float* __restrict__ be, const u16* __restrict__ inlb,
                                            const int* __restrict__ src, const int* __restrict__ perm,
                                            u16* __restrict__ imP){
  __shared__ __align__(16) u16 efs[64*LDE];
  __shared__ float os[64*68];
  const int t = threadIdx.x;
  const int ebase = blockIdx.x*64;
  { // stage edge_feat bf16 (coalesced float4 reads); wave-local rows
    int e=t>>2, k0=(t&3)*8;
    const float* p = ef + (size_t)(ebase+e)*32 + k0;
    float4 v0=*(const float4*)p, v1=*(const float4*)(p+4);
    uint4 pk = make_uint4(pack2(v0.x,v0.y),pack2(v0.z,v0.w),pack2(v1.x,v1.y),pack2(v1.z,v1.w));
    *(uint4*)&efs[e*LDE + k0] = pk;
  }
  { // MFMA 16x16x32 (K=32, one step); B fragments from global, coalesced
    int w=t>>6, lane=t&63, q=lane>>4, mr=lane&15;
    int rowb=w*16;
    bf16x8 A = *(const bf16x8*)&efs[(rowb+mr)*LDE + q*8];
    #pragma unroll
    for (int nt=0;nt<4;nt++){
      bf16x8 B = *(const bf16x8*)(weB + nt*512 + lane*8);
      f32x4 acc = {0.f,0.f,0.f,0.f};
      acc = __builtin_amdgcn_mfma_f32_16x16x32_bf16(A,B,acc,0,0,0);
      #pragma unroll
      for (int r=0;r<4;r++) os[(rowb+q*4+r)*68 + nt*16+mr] = acc[r];
    }
  }
  { // epilogue: + be + inlb[src[e]] -> bf16, full-row scatter to imP[perm[e]]
    int e=t>>2, d0=(t&3)*16;
    const size_t eg = (size_t)(ebase+e);
    const int s = src[eg], ps = perm[eg];
    const u16* ip = inlb + (size_t)s*D + d0;
    uint4 iv0 = *(const uint4*)ip, iv1 = *(const uint4*)(ip+8);
    float il[16]; unpack8(iv0,il); unpack8(iv1,il+8);
    float x[16];
    #pragma unroll
    for (int j=0;j<16;j++) x[j] = os[e*68 + d0 + j] + be[d0+j] + il[j];
    uint4 p0 = make_uint4(pack2(x[0],x[1]),pack2(x[2],x[3]),pack2(x[4],x[5]),pack2(x[6],x[7]));
    uint4 p1 = make_uint4(pack2(x[8],x[9]),pack2(x[10],x[11]),pack2(x[12],x[13]),pack2(x[14],x[15]));
    u16* op = imP + (size_t)ps*D + d0;
    *(uint4*)op = p0; *(uint4*)(op+8) = p1;
  }
}

// ---------------- iteration kernel: 64 slots/block, ZERO barriers ----------------
// MODE 0: x=relu(imP[slot]);                                   revOut[prevP[slot]]=fp8(x@Wc); naWb_out += per-node (pk bf16)
// MODE 1: x=relu(naWb[srcP] - fp8dec(revIn[slot]) + bc + imP[slot]); same outputs
template<int MODE>
__global__ __launch_bounds__(256) void k_iter(const u16* __restrict__ imP, const u8* __restrict__ revIn,
      const u16* __restrict__ naWb, const u16* __restrict__ wcB, const float* __restrict__ bc,
      const int* __restrict__ srcP, const int* __restrict__ prevP, const int* __restrict__ nodeP,
      u8* __restrict__ revOut, u16* __restrict__ naWb_out){
  __shared__ __align__(16) u16 xs[64*LDW];
  __shared__ __align__(16) u16 os[64*LDO];
  __shared__ int nid[64];
  const int t = threadIdx.x;
  const int lane = t&63, w = t>>6;
  const size_t sbase = (size_t)blockIdx.x*64;
  if (lane < 16) nid[w*16 + lane] = nodeP[sbase + w*16 + lane];   // wave-local
  { // phase 1: stream reads + bf16 naWb row gather + fp8 rev decode; xs rows wave-local
    const int e = t>>2, d0 = (t&3)*16;
    const size_t slot = sbase + e;
    const u16* ip = imP + slot*D + d0;
    uint4 r0 = *(const uint4*)ip, r1 = *(const uint4*)(ip+8);
    float x[16]; unpack8(r0,x); unpack8(r1,x+8);
    if (MODE == 1){
      const int sp = srcP[slot];
      const u8* cp = revIn + slot*D + d0;          // 16 fp8 bytes
      uint4 c = *(const uint4*)cp;
      const u16* np_ = naWb + (size_t)sp*D + d0;
      uint4 n0=*(const uint4*)np_, n1=*(const uint4*)(np_+8);
      float cv[16], nv[16];
      dec16(c, cv);
      unpack8(n0,nv); unpack8(n1,nv+8);
      #pragma unroll
      for (int j=0;j<16;j++) x[j] += nv[j] - cv[j] + bc[d0+j];
    }
    #pragma unroll
    for (int j=0;j<16;j++) x[j] = x[j]>0.f ? x[j] : 0.f;
    uint4 p0 = make_uint4(pack2(x[0],x[1]),pack2(x[2],x[3]),pack2(x[4],x[5]),pack2(x[6],x[7]));
    uint4 p1 = make_uint4(pack2(x[8],x[9]),pack2(x[10],x[11]),pack2(x[12],x[13]),pack2(x[14],x[15]));
    u16* qd = &xs[e*LDW + d0];
    *(uint4*)qd = p0; *(uint4*)(qd+8) = p1;
  }
  { // phase 2: MFMA (xs wave-local, no barrier); fp8 scatter store + fused bf16 flush
    const int q = lane>>4, mr = lane&15;
    const int rowb = w*16;
    bf16x8 A0 = *(const bf16x8*)&xs[(rowb+mr)*LDW + q*8];
    bf16x8 A1 = *(const bf16x8*)&xs[(rowb+mr)*LDW + 32 + q*8];
    #pragma unroll
    for (int nt=0;nt<4;nt++){
      bf16x8 B0 = *(const bf16x8*)(wcB + nt*1024 + lane*8);
      bf16x8 B1 = *(const bf16x8*)(wcB + nt*1024 + 512 + lane*8);
      f32x4 acc = {0.f,0.f,0.f,0.f};
      acc = __builtin_amdgcn_mfma_f32_16x16x32_bf16(A0,B0,acc,0,0,0);
      acc = __builtin_amdgcn_mfma_f32_16x16x32_bf16(A1,B1,acc,0,0,0);
      #pragma unroll
      for (int r=0;r<4;r++) os[(rowb+q*4+r)*LDO + nt*16 + mr] = f2b(acc[r]);
    }
    const int lr = lane>>2, cc = lane&3;
    const int tgt = prevP[sbase + rowb + lr];
    { // encode 16 bf16 -> 16 fp8, single uint4 scatter write
      float yv[16];
      const u16* osp = &os[(rowb+lr)*LDO + cc*16];
      uint4 o0 = *(const uint4*)osp, o1 = *(const uint4*)(osp+8);
      unpack8(o0,yv); unpack8(o1,yv+8);
      uint4 pk8;
      pk8.x = f2e4m3_4(yv);    pk8.y = f2e4m3_4(yv+4);
      pk8.z = f2e4m3_4(yv+8);  pk8.w = f2e4m3_4(yv+12);
      u8* gp = revOut + (size_t)tgt*D + cc*16;
      *(uint4*)gp = pk8;
    }
    // fused per-node reduction (wave-local os + nid); packed bf16 atomic flush
    float acc = 0.f;
    int curn = nid[rowb];
    #pragma unroll 4
    for (int i=0;i<16;++i){
      int n = nid[rowb+i];                 // wave-uniform
      if (n != curn){
        float hi = __shfl_xor(acc, 1, 64);
        if (!(lane&1)) atomic_pk_bf16(naWb_out + (size_t)curn*D + lane, acc, hi);
        curn = n; acc = 0.f;
      }
      acc += b2f(os[(rowb+i)*LDO + lane]);
    }
    float hi = __shfl_xor(acc, 1, 64);
    if (!(lane&1)) atomic_pk_bf16(naWb_out + (size_t)curn*D + lane, acc, hi);
  }
}

// ---------------- final BP step (barrier-free): e2nb += per-node (pk bf16) ----------------
__global__ __launch_bounds__(256) void k_last(const u16* __restrict__ imP, const u8* __restrict__ revIn,
      const u16* __restrict__ naWb, const float* __restrict__ bc,
      const int* __restrict__ srcP, const int* __restrict__ nodeP,
      u16* __restrict__ e2nb){
  __shared__ __align__(16) u16 xs[64*LDW];
  __shared__ int nid[64];
  const int t = threadIdx.x;
  const int lane = t&63, w = t>>6;
  const size_t sbase = (size_t)blockIdx.x*64;
  if (lane < 16) nid[w*16+lane] = nodeP[sbase + w*16 + lane];   // wave-local
  {
    const int e = t>>2, d0 = (t&3)*16;
    const size_t slot = sbase + e;
    const u16* ip = imP + slot*D + d0;
    uint4 r0 = *(const uint4*)ip, r1 = *(const uint4*)(ip+8);
    float x[16]; unpack8(r0,x); unpack8(r1,x+8);
    const int sp = srcP[slot];
    const u8* cp = revIn + slot*D + d0;
    uint4 c = *(const uint4*)cp;
    const u16* np_ = naWb + (size_t)sp*D + d0;
    uint4 n0 = *(const uint4*)np_, n1 = *(const uint4*)(np_+8);
    float cv[16], nv[16];
    dec16(c, cv);
    unpack8(n0,nv); unpack8(n1,nv+8);
    #pragma unroll
    for (int j=0;j<16;j++){ x[j] += nv[j] - cv[j] + bc[d0+j]; x[j] = x[j]>0.f ? x[j] : 0.f; }
    uint4 p0 = make_uint4(pack2(x[0],x[1]),pack2(x[2],x[3]),pack2(x[4],x[5]),pack2(x[6],x[7]));
    uint4 p1 = make_uint4(pack2(x[8],x[9]),pack2(x[10],x[11]),pack2(x[12],x[13]),pack2(x[14],x[15]));
    u16* qd = &xs[e*LDW + d0];
    *(uint4*)qd = p0; *(uint4*)(qd+8) = p1;
  }
  { // wave-local reduction; packed bf16 atomic flush
    float acc = 0.f;
    int curn = nid[w*16];
    #pragma unroll 4
    for (int i=0;i<16;++i){
      int n = nid[w*16+i];
      if (n != curn){
        float hi = __shfl_xor(acc, 1, 64);
        if (!(lane&1)) atomic_pk_bf16(e2nb + (size_t)curn*D + lane, acc, hi);
        curn = n; acc = 0.f;
      }
      acc += b2f(xs[(w*16+i)*LDW + lane]);
    }
    float hi = __shfl_xor(acc, 1, 64);
    if (!(lane&1)) atomic_pk_bf16(e2nb + (size_t)curn*D + lane, acc, hi);
  }
}

// ---------------- CSR build ----------------
__global__ __launch_bounds__(1024) void k_scan1(const int* __restrict__ cnt, int* __restrict__ outv,
                                                int* __restrict__ bsums, int n){
  __shared__ int sh[1024];
  int i = blockIdx.x*1024 + threadIdx.x;
  int v = (i<n)? cnt[i] : 0;
  sh[threadIdx.x]=v;
  __syncthreads();
  for (int off=1; off<1024; off<<=1){
    int tv = (threadIdx.x>=(unsigned)off)? sh[threadIdx.x-off] : 0;
    __syncthreads();
    sh[threadIdx.x] += tv;
    __syncthreads();
  }
  if (i<n) outv[i] = sh[threadIdx.x] - v;
  if (threadIdx.x==1023) bsums[blockIdx.x] = sh[1023];
}
__global__ __launch_bounds__(1024) void k_scan3(int* __restrict__ off, int* __restrict__ cur,
                                                const int* __restrict__ bsums, int n){
  __shared__ int spref;
  if (threadIdx.x < 64){
    int v = ((int)threadIdx.x < (int)blockIdx.x) ? bsums[threadIdx.x] : 0;
    #pragma unroll
    for (int o=1;o<64;o<<=1) v += __shfl_xor(v, o, 64);
    if (threadIdx.x==0) spref = v;
  }
  __syncthreads();
  int i = blockIdx.x*1024 + threadIdx.x;
  if (i<n){ int v = off[i] + spref; off[i]=v; cur[i]=v; }
}
__global__ void k_fill(const int* __restrict__ dst, const int* __restrict__ src,
                       int* __restrict__ cur, int* __restrict__ perm,
                       int* __restrict__ srcP, int* __restrict__ nodeP){
  int e = blockIdx.x*256 + threadIdx.x;
  int d = dst[e];
  int pos = atomicAdd(&cur[d], 1);
  perm[e] = pos;
  srcP[pos] = src[e];
  nodeP[pos] = d;
}
__global__ void k_prev(const int* __restrict__ rev, const int* __restrict__ perm, int* __restrict__ prevP){
  int e = blockIdx.x*256 + threadIdx.x;
  prevP[perm[e]] = perm[rev[e]];
}

// ---------------- MFMA final: relu(e2nb)@Wo, +bo, relu, gid run-reduction -> yacc ----------------
__global__ __launch_bounds__(256) void k_finalM(const u16* __restrict__ e2nb, const u16* __restrict__ woB,
                                                const float* __restrict__ bo, const int* __restrict__ gid,
                                                float* __restrict__ yacc){
  __shared__ __align__(16) u16 xs[64*LDW];
  __shared__ float os[64*68];
  __shared__ int gidS[64];
  const int t = threadIdx.x;
  const int lane = t&63, w = t>>6;
  const int nbase = blockIdx.x*64;
  if (lane < 16){
    int n = nbase + w*16 + lane;
    gidS[w*16 + lane] = (n < NN) ? gid[n] : -1;      // wave-local
  }
  { // phase 1: load e2nb row, relu -> xs (zeros for padded nodes)
    const int e = t>>2, d0 = (t&3)*16;
    const int n = nbase + e;
    float x[16];
    if (n < NN){
      const u16* ip = e2nb + (size_t)n*D + d0;
      uint4 r0 = *(const uint4*)ip, r1 = *(const uint4*)(ip+8);
      unpack8(r0,x); unpack8(r1,x+8);
      #pragma unroll
      for (int j=0;j<16;j++) x[j] = x[j]>0.f ? x[j] : 0.f;
    } else {
      #pragma unroll
      for (int j=0;j<16;j++) x[j] = 0.f;
    }
    uint4 p0 = make_uint4(pack2(x[0],x[1]),pack2(x[2],x[3]),pack2(x[4],x[5]),pack2(x[6],x[7]));
    uint4 p1 = make_uint4(pack2(x[8],x[9]),pack2(x[10],x[11]),pack2(x[12],x[13]),pack2(x[14],x[15]));
    u16* qd = &xs[e*LDW + d0];
    *(uint4*)qd = p0; *(uint4*)(qd+8) = p1;
  }
  { // phase 2: MFMA xs@Wo (K=64) -> os fp32; +bo,relu inside run-reduction
    const int q = lane>>4, mr = lane&15;
    const int rowb = w*16;
    bf16x8 A0 = *(const bf16x8*)&xs[(rowb+mr)*LDW + q*8];
    bf16x8 A1 = *(const bf16x8*)&xs[(rowb+mr)*LDW + 32 + q*8];
    #pragma unroll
    for (int nt=0;nt<4;nt++){
      bf16x8 B0 = *(const bf16x8*)(woB + nt*1024 + lane*8);
      bf16x8 B1 = *(const bf16x8*)(woB + nt*1024 + 512 + lane*8);
      f32x4 acc = {0.f,0.f,0.f,0.f};
      acc = __builtin_amdgcn_mfma_f32_16x16x32_bf16(A0,B0,acc,0,0,0);
      acc = __builtin_amdgcn_mfma_f32_16x16x32_bf16(A1,B1,acc,0,0,0);
      #pragma unroll
      for (int r=0;r<4;r++) os[(rowb+q*4+r)*68 + nt*16 + mr] = acc[r];
    }
    const float bol = bo[lane];
    float acc = 0.f;
    int curg = gidS[rowb];
    #pragma unroll 4
    for (int i=0;i<16;++i){
      int g = gidS[rowb+i];                // wave-uniform
      if (g != curg){
        if (curg >= 0) atomicAdd(&yacc[curg*D + lane], acc);
        curg = g; acc = 0.f;
      }
      if (g >= 0){
        float v = os[(rowb+i)*68 + lane] + bol;
        acc += v>0.f ? v : 0.f;
      }
    }
    if (curg >= 0) atomicAdd(&yacc[curg*D + lane], acc);
  }
}
__global__ void k_out(const float* __restrict__ yacc, float* __restrict__ outp){
  int i = blockIdx.x*256 + threadIdx.x;
  if (i<NG*D){ float v=yacc[i]; outp[i]= v>0.f?v:0.f; }
}

// ---------------- workspace layout ----------------
static constexpr size_t SZ_E   = (size_t)NE*D*2;          // 102.4 MB bf16 edge array
static constexpr size_t SZ_E8  = (size_t)NE*D;            // 51.2 MB fp8 edge array
static constexpr size_t SZ_NB  = (size_t)NN*D*2;          // 6.4 MB bf16 node array
static constexpr size_t OFF_IMP  = 0;
static constexpr size_t OFF_RVA  = SZ_E;
static constexpr size_t OFF_RVB  = OFF_RVA + SZ_E8;
// contiguous zero region: csr_cur | yacc | nb0 | nb1 | nb2 | e2nb
static constexpr size_t OFF_CCUR = OFF_RVB + SZ_E8;
static constexpr size_t OFF_YACC = OFF_CCUR + 200064;
static constexpr size_t OFF_NB0  = OFF_YACC + (size_t)NG*D*4;
static constexpr size_t OFF_NB1  = OFF_NB0 + SZ_NB;
static constexpr size_t OFF_NB2  = OFF_NB1 + SZ_NB;
static constexpr size_t OFF_E2NB = OFF_NB2 + SZ_NB;
static constexpr size_t ZERO_SZ  = 200064 + (size_t)NG*D*4 + 4*SZ_NB;
static constexpr size_t OFF_INL  = OFF_E2NB + SZ_NB;
static constexpr size_t OFF_COFF = OFF_INL + SZ_NB;
static constexpr size_t OFF_PERM = OFF_COFF + 200064;
static constexpr size_t OFF_SRCP = OFF_PERM + (size_t)NE*4;
static constexpr size_t OFF_PRVP = OFF_SRCP + (size_t)NE*4;
static constexpr size_t OFF_NODP = OFF_PRVP + (size_t)NE*4;
static constexpr size_t OFF_BS   = OFF_NODP + (size_t)NE*4;
static constexpr size_t OFF_WCT  = OFF_BS + 256;               // wcB: 8192 B
static constexpr size_t OFF_WET  = OFF_WCT + 8192;             // weB: 4096 B
static constexpr size_t OFF_WOT  = OFF_WET + 4096;             // woB: 8192 B

extern "C" void kernel_launch(void* const* d_in, const int* in_sizes, int n_in,
                              void* d_out, int out_size, void* d_ws, size_t ws_size,
                              hipStream_t stream) {
  const float* node_feat = (const float*)d_in[0];
  const float* edge_feat = (const float*)d_in[1];
  const int*   src       = (const int*)d_in[2];
  const int*   dst       = (const int*)d_in[3];
  const int*   rev       = (const int*)d_in[4];
  const int*   gid       = (const int*)d_in[5];
  const float* Wn = (const float*)d_in[7];
  const float* bn = (const float*)d_in[8];
  const float* We = (const float*)d_in[9];
  const float* be = (const float*)d_in[10];
  const float* Wc = (const float*)d_in[11];
  const float* bc = (const float*)d_in[12];
  const float* Wo = (const float*)d_in[13];
  const float* bo = (const float*)d_in[14];

  char* ws = (char*)d_ws;
  u16*   imP     = (u16*)(ws + OFF_IMP);
  u8*    revA    = (u8*)(ws + OFF_RVA);
  u8*    revB    = (u8*)(ws + OFF_RVB);
  float* yacc    = (float*)(ws + OFF_YACC);
  u16*   nb0     = (u16*)(ws + OFF_NB0);
  u16*   nb1     = (u16*)(ws + OFF_NB1);
  u16*   nb2     = (u16*)(ws + OFF_NB2);
  u16*   e2nb    = (u16*)(ws + OFF_E2NB);
  u16*   inlb    = (u16*)(ws + OFF_INL);
  int*   csr_off = (int*)(ws + OFF_COFF);
  int*   csr_cur = (int*)(ws + OFF_CCUR);
  int*   perm    = (int*)(ws + OFF_PERM);
  int*   srcP    = (int*)(ws + OFF_SRCP);
  int*   prevP   = (int*)(ws + OFF_PRVP);
  int*   nodeP   = (int*)(ws + OFF_NODP);
  int*   bsums   = (int*)(ws + OFF_BS);
  u16*   wcB     = (u16*)(ws + OFF_WCT);
  u16*   weB     = (u16*)(ws + OFF_WET);
  u16*   woB     = (u16*)(ws + OFF_WOT);

  // one upfront memset: csr_cur + yacc + nb0/nb1/nb2 + e2nb
  hipMemsetAsync(ws + OFF_CCUR, 0, ZERO_SZ, stream);

  // merged: node linear + weight fragments + dst histogram
  k_pi0<<<15665, 256, 0, stream>>>(node_feat, Wn, bn, Wc, We, Wo, dst, inlb, wcB, weB, woB, csr_cur);

  // CSR build
  k_scan1<<<49, 1024, 0, stream>>>(csr_cur, csr_off, bsums, NN);
  k_scan3<<<49, 1024, 0, stream>>>(csr_off, csr_cur, bsums, NN);
  k_fill <<<NE/256, 256, 0, stream>>>(dst, src, csr_cur, perm, srcP, nodeP);
  k_prev <<<NE/256, 256, 0, stream>>>(rev, perm, prevP);

  // front end
  k_im  <<<NE/64, 256, 0, stream>>>(edge_feat, weB, be, inlb, src, perm, imP);

  // loopy BP: fp8 rev exchange, pk-bf16 node agg, triple-buffered naWb
  k_iter<0><<<NE/64, 256, 0, stream>>>(imP, revA, nb0, wcB, bc, srcP, prevP, nodeP, revA, nb0);
  k_iter<1><<<NE/64, 256, 0, stream>>>(imP, revA, nb0, wcB, bc, srcP, prevP, nodeP, revB, nb1);
  k_iter<1><<<NE/64, 256, 0, stream>>>(imP, revB, nb1, wcB, bc, srcP, prevP, nodeP, revA, nb2);
  k_last<<<NE/64, 256, 0, stream>>>(imP, revA, nb2, bc, srcP, nodeP, e2nb);

  // head (MFMA final + out)
  k_finalM<<<(NN+63)/64, 256, 0, stream>>>(e2nb, woB, bo, gid, yacc);
  k_out<<<(NG*D)/256, 256, 0, stream>>>(yacc, (float*)d_out);
}